// Round 2
// baseline (13710.196 us; speedup 1.0000x reference)
//
#include <hip/hip_runtime.h>
#include <hip/hip_bf16.h>
#include <math.h>

// ---------------------------------------------------------------------------
// BabiUTransformer (Universal Transformer + ACT) on gfx950.  All float I/O fp32.
// GEMMs: split-precision bf16 MFMA (hh+lh+hl, err ~2^-18 rel). Activations are
// pre-split into hi/lo bf16 planes by their PRODUCER kernels.
// GEMM v3 (this round): 128x128 tile, BK=32, 4 waves (64x64 quadrant each,
// 4x4 fragments), global_load_lds width-16 staging, and DOUBLE-BUFFERED LDS
// with raw s_barrier + asm vmcnt(0) AFTER the MFMA phase (T3-minimal).
// Rationale: round-1 counters showed 1 block/CU on the N=512 GEMMs (grid 284)
// -> the __syncthreads() vmcnt(0) drain between load-issue and compute was
// fully latency-exposed (MfmaUtil 16.7%). Pipelining the prefetch under the
// MFMA phase hides it without needing multi-block TLP.
// LDS layout is [group16][kchunk8][row16] subtiles so fragment ds_read_b128s
// are 1KiB-contiguous per wave (conflict-free, verified: 0 conflicts in r1);
// the lane permutation is carried on the per-lane GLOBAL source address.
// Conv edge zero-fill via per-lane redirect of the source pointer to a
// zeroed 256B page (numerically identical to register zero-fill).
// Attention: LDS stride padded 64->65 (kills 64-way bank conflict).
// ACT any()-gate via per-step device flag (ballot-reduced).
// ---------------------------------------------------------------------------

typedef unsigned short ushort_t;
using short8  = __attribute__((ext_vector_type(8))) short;
using floatx4 = __attribute__((ext_vector_type(4))) float;

#define B_   256
#define L_   71
#define H_   512
#define M_   (B_*L_)      // 18176 rows (142 x 128); half = 9088 (71 x 128)
#define MH_  9088
#define FS_  2048
#define V_   32000
#define NH_  8
#define DK_  64

__device__ inline ushort_t f2bf_rne(float f) {
    unsigned u = __float_as_uint(f);
    return (ushort_t)((u + 0x7FFFu + ((u >> 16) & 1u)) >> 16);
}

// async global->LDS, 16B per lane. LDS dest must be wave-uniform base
// (hardware writes base + lane*16); global src is per-lane.
__device__ __forceinline__ void gload16(const void* g, void* l)
{
    __builtin_amdgcn_global_load_lds(
        (__attribute__((address_space(1))) unsigned int*)(g),
        (__attribute__((address_space(3))) unsigned int*)(l),
        16, 0, 0);
}

// ---------------------------------------------------------------------------
// Split GEMM: C[M,N] = alpha*(A @ B) (+bias)(+residual)(relu)
// A pre-split hi/lo bf16 planes [rows, lda]. B hi/lo planes [N,K] row-major.
// conv=1: row m's 3C window starts at A row (am+rowA-1); k-chunk d==0 invalid
//   at l==0, d==2 invalid at l==70 (zero via zpg redirect). l from (am+rowG)%71.
// outMode: 0 = f32 out; 1 = f32 out + fused prev-update; 2 = bf16 hi/lo out.
// Tile 128x128, BK=32, double-buffered. Grid: (N/128, M/128). 256 threads.
// ---------------------------------------------------------------------------
__global__ __launch_bounds__(256) void gemm_s(
    const ushort_t* __restrict__ AH, const ushort_t* __restrict__ AL,
    int lda, int conv, int rowA, int rowG,
    const ushort_t* __restrict__ Bh, const ushort_t* __restrict__ Bl,
    int N, int K,
    const float* __restrict__ bias, const float* residual,
    float alpha, int relu, int rowC, int outMode,
    float* Cout, ushort_t* CoutH, ushort_t* CoutL,
    float* prev, const float* __restrict__ uw,
    const ushort_t* __restrict__ zpg)
{
    // per plane per buffer: 8 groups x [4 kchunks x 16 rows] x 8 shorts = 8KB
    __shared__ __attribute__((aligned(16))) short Ahs[2][4096], Als[2][4096];
    __shared__ __attribute__((aligned(16))) short Bhs[2][4096], Bls[2][4096];

    const int tid  = threadIdx.x;
    const int w    = tid >> 6, lane = tid & 63;
    const int bm = blockIdx.y << 7, bn = blockIdx.x << 7;

    // ---- staging setup: wave w stages groups {w, w+4} of each plane ----
    const int srow = lane & 15;        // row within 16-row group
    const int skc  = lane >> 4;        // k-chunk (8 shorts) 0..3
    const int ra0  = w * 16 + srow;    // tile rows this thread stages
    const int ra1  = ra0 + 64;
    const int am0  = bm + ra0, am1 = bm + ra1;
    const int ash  = conv ? (rowA - 1) : rowA;
    const ushort_t* pAh0 = AH + (long)(am0 + ash) * lda + skc * 8;
    const ushort_t* pAl0 = AL + (long)(am0 + ash) * lda + skc * 8;
    const ushort_t* pAh1 = AH + (long)(am1 + ash) * lda + skc * 8;
    const ushort_t* pAl1 = AL + (long)(am1 + ash) * lda + skc * 8;
    int l0 = 0, l1 = 0;
    if (conv) { l0 = (am0 + rowG) % 71; l1 = (am1 + rowG) % 71; }
    const ushort_t* pBh0 = Bh + (long)(bn + ra0) * K + skc * 8;
    const ushort_t* pBl0 = Bl + (long)(bn + ra0) * K + skc * 8;
    const ushort_t* pBh1 = Bh + (long)(bn + ra1) * K + skc * 8;
    const ushort_t* pBl1 = Bl + (long)(bn + ra1) * K + skc * 8;

    // ---- fragment read offsets: wave reads 1KiB contiguous (conflict-free) ----
    const int quad = lane >> 4, mr = lane & 15;
    const int wr = (w >> 1) << 6, wc = (w & 1) << 6;   // wave quadrant origin
    const int aoff = (wr >> 4) * 512 + quad * 128 + mr * 8;  // + i*512 (shorts)
    const int boff = (wc >> 4) * 512 + quad * 128 + mr * 8;  // + j*512

    floatx4 acc[4][4] = {};

    const int NT = K >> 5;

    auto stage = [&](int buf, int t) {
        const int k0 = t << 5;
        const ushort_t* sA0h = pAh0 + k0;
        const ushort_t* sA0l = pAl0 + k0;
        const ushort_t* sA1h = pAh1 + k0;
        const ushort_t* sA1l = pAl1 + k0;
        if (conv) {
            // lda is a multiple of 32 -> d uniform across the K-step
            const int d = (k0 >= lda) ? ((k0 >= 2 * lda) ? 2 : 1) : 0;
            if ((l0 == 0 && d == 0) || (l0 == 70 && d == 2)) { sA0h = zpg; sA0l = zpg; }
            if ((l1 == 0 && d == 0) || (l1 == 70 && d == 2)) { sA1h = zpg; sA1l = zpg; }
        }
        gload16(sA0h,      &Ahs[buf][w * 512]);
        gload16(sA1h,      &Ahs[buf][(w + 4) * 512]);
        gload16(sA0l,      &Als[buf][w * 512]);
        gload16(sA1l,      &Als[buf][(w + 4) * 512]);
        gload16(pBh0 + k0, &Bhs[buf][w * 512]);
        gload16(pBh1 + k0, &Bhs[buf][(w + 4) * 512]);
        gload16(pBl0 + k0, &Bls[buf][w * 512]);
        gload16(pBl1 + k0, &Bls[buf][(w + 4) * 512]);
    };

    auto compute = [&](int buf) {
        short8 ah[4], al[4], bh[4], bl[4];
        #pragma unroll
        for (int i = 0; i < 4; i++) {
            ah[i] = *(const short8*)(&Ahs[buf][aoff + i * 512]);
            al[i] = *(const short8*)(&Als[buf][aoff + i * 512]);
            bh[i] = *(const short8*)(&Bhs[buf][boff + i * 512]);
            bl[i] = *(const short8*)(&Bls[buf][boff + i * 512]);
        }
        #pragma unroll
        for (int i = 0; i < 4; i++)
        #pragma unroll
        for (int j = 0; j < 4; j++) {
            acc[i][j] = __builtin_amdgcn_mfma_f32_16x16x32_bf16(ah[i], bh[j], acc[i][j], 0, 0, 0);
            acc[i][j] = __builtin_amdgcn_mfma_f32_16x16x32_bf16(al[i], bh[j], acc[i][j], 0, 0, 0);
            acc[i][j] = __builtin_amdgcn_mfma_f32_16x16x32_bf16(ah[i], bl[j], acc[i][j], 0, 0, 0);
        }
    };

    // prologue: fill buf0, drain, publish
    stage(0, 0);
    asm volatile("s_waitcnt vmcnt(0)" ::: "memory");
    __builtin_amdgcn_s_barrier();

    int cur = 0;
    for (int t = 0; t < NT - 1; ++t) {
        stage(cur ^ 1, t + 1);   // prefetch next tile (lands under the MFMAs)
        compute(cur);
        asm volatile("s_waitcnt vmcnt(0)" ::: "memory");
        __builtin_amdgcn_s_barrier();
        cur ^= 1;
    }
    compute(cur);                // epilogue tile, no prefetch

    // C/D layout: col = lane&15, row = quad*4 + r  [verified m89/m91]
    #pragma unroll
    for (int j = 0; j < 4; j++) {
        const int gcol = bn + wc + j * 16 + mr;
        const float bv = bias ? bias[gcol] : 0.f;
        #pragma unroll
        for (int i = 0; i < 4; i++) {
            #pragma unroll
            for (int r = 0; r < 4; r++) {
                const int grow = bm + wr + i * 16 + quad * 4 + r;
                const long crow = (long)grow + rowC;
                float v = acc[i][j][r] * alpha + bv;
                if (residual) v += residual[crow * N + gcol];
                if (relu) v = fmaxf(v, 0.f);
                const long cidx = crow * (long)N + gcol;
                if (outMode == 2) {
                    ushort_t h = f2bf_rne(v);
                    float hf = __uint_as_float(((unsigned)h) << 16);
                    CoutH[cidx] = h;
                    CoutL[cidx] = f2bf_rne(v - hf);
                } else {
                    Cout[cidx] = v;
                    if (outMode == 1) {
                        float u = uw[crow];
                        prev[cidx] = v * u + prev[cidx] * (1.f - u);
                    }
                }
            }
        }
    }
}

// Timing-signal tables, float32 math (matches numpy float32 exp/sin chain).
__global__ __launch_bounds__(256) void sig_prep(float* __restrict__ T, float* __restrict__ P)
{
    int i = blockIdx.x * 256 + threadIdx.x;
    const int NT = 71 * 512;
    if (i >= NT + 6 * 512) return;
    int pos, c, idx;
    float* dst;
    if (i < NT) { pos = i >> 9; c = i & 511; dst = T; idx = i; }
    else        { int j = i - NT; pos = j >> 9; c = j & 511; dst = P; idx = j; }
    const float loginc = 0.036119766f;
    int jj = c & 255;
    float inv = expf(-(float)jj * loginc);
    float arg = (float)pos * inv;
    dst[idx] = (c < 256) ? sinf(arg) : cosf(arg);
}

// active-gate: flag |= any(hp<0.9 && nu<6)   (ballot, 1 atomic/wave)
__global__ __launch_bounds__(256) void gate_kernel(
    const float* __restrict__ hp, const float* __restrict__ nu, int* __restrict__ flag)
{
    int i = blockIdx.x * 256 + threadIdx.x;
    bool act = (i < M_) && (hp[i] < 0.9f) && (nu[i] < 6.0f);
    unsigned long long b = __ballot(act);
    if ((threadIdx.x & 63) == 0 && b) atomicOr(flag, 1);
}

// s = state + T[l] + P[t] (in-place); pr = sigmoid(s.p_w+p_b); gated ACT.
__global__ __launch_bounds__(256) void s_pr_kernel(
    float* trunk, const float* __restrict__ Ttab, const float* __restrict__ Ptab,
    const float* __restrict__ p_w, const float* __restrict__ p_b,
    float* __restrict__ hp, float* __restrict__ rem, float* __restrict__ nu,
    float* __restrict__ uw, const int* __restrict__ flag, int t)
{
    const int row  = blockIdx.x * 4 + (threadIdx.x >> 6);
    const int lane = threadIdx.x & 63;
    const int l    = row % 71;
    float dot = 0.f;
    #pragma unroll
    for (int j = 0; j < 8; j++) {
        int c  = lane + 64 * j;
        float sv = trunk[(long)row * H_ + c] + Ttab[l * H_ + c] + Ptab[t * H_ + c];
        trunk[(long)row * H_ + c] = sv;
        dot += sv * p_w[c];
    }
    #pragma unroll
    for (int o = 32; o; o >>= 1) dot += __shfl_xor(dot, o);
    if (lane == 0) {
        if (flag[0]) {
            float pr = 1.f / (1.f + expf(-(dot + p_b[0])));
            float hp0 = hp[row], rem0 = rem[row], nu0 = nu[row];
            float still = (hp0 < 1.0f) ? 1.f : 0.f;
            float tot   = hp0 + pr * still;
            float nh    = ((tot > 0.9f) ? 1.f : 0.f) * still;
            float st2   = ((tot <= 0.9f) ? 1.f : 0.f) * still;
            float hp2   = hp0 + pr * st2;
            float rem2  = rem0 + nh * (1.f - hp2);
            hp2 += nh * rem2;
            hp[row] = hp2; rem[row] = rem2; nu[row] = nu0 + st2 + nh;
            uw[row] = pr * st2 + nh * rem2;
        } else {
            uw[row] = 0.f;
        }
    }
}

// LayerNorm fp32 -> bf16 hi/lo planes.
__global__ __launch_bounds__(256) void ln_kernel(
    const float* __restrict__ X, const float* __restrict__ g,
    const float* __restrict__ bb, ushort_t* __restrict__ outH,
    ushort_t* __restrict__ outL)
{
    const int row  = blockIdx.x * 4 + (threadIdx.x >> 6);
    const int lane = threadIdx.x & 63;
    const float* xr = X + (long)row * H_;
    float v[8];
    float s = 0.f;
    #pragma unroll
    for (int j = 0; j < 8; j++) { v[j] = xr[lane + 64 * j]; s += v[j]; }
    #pragma unroll
    for (int o = 32; o; o >>= 1) s += __shfl_xor(s, o);
    float mean = s * (1.f / 512.f);
    float q = 0.f;
    #pragma unroll
    for (int j = 0; j < 8; j++) { float d = v[j] - mean; q += d * d; }
    #pragma unroll
    for (int o = 32; o; o >>= 1) q += __shfl_xor(q, o);
    float sd  = sqrtf(q * (1.f / 511.f));
    float inv = 1.f / (sd + 1e-6f);
    #pragma unroll
    for (int j = 0; j < 8; j++) {
        int c = lane + 64 * j;
        float val = g[c] * (v[j] - mean) * inv + bb[c];
        ushort_t h = f2bf_rne(val);
        float hf = __uint_as_float(((unsigned)h) << 16);
        long idx = (long)row * H_ + c;
        outH[idx] = h;
        outL[idx] = f2bf_rne(val - hf);
    }
}

// Attention, fp32, LDS stride 65 (conflict-free). One block per (b,h).
// q pre-scaled by 1/8 in the q-GEMM. ctx written as bf16 hi/lo planes.
__global__ __launch_bounds__(256) void attn_kernel(
    const float* __restrict__ q, const float* __restrict__ k,
    const float* __restrict__ v, ushort_t* __restrict__ ctxH,
    ushort_t* __restrict__ ctxL)
{
    __shared__ float qs[L_ * 65];
    __shared__ float ks[L_ * 65];   // reused for V
    __shared__ float Ss[L_ * L_];
    const int tid = threadIdx.x;
    const int b = blockIdx.x >> 3, h = blockIdx.x & 7;
    const long base = (long)b * L_ * H_ + h * DK_;
    for (int idx = tid; idx < L_ * DK_; idx += 256) {
        int i = idx >> 6, d = idx & 63;
        qs[i * 65 + d] = q[base + (long)i * H_ + d];
        ks[i * 65 + d] = k[base + (long)i * H_ + d];
    }
    __syncthreads();
    for (int idx = tid; idx < L_ * L_; idx += 256) {
        int i = idx / 71, j = idx % 71;
        const float* qr = qs + i * 65;
        const float* kr = ks + j * 65;
        float s0 = 0.f, s1 = 0.f, s2 = 0.f, s3 = 0.f;
        #pragma unroll
        for (int d = 0; d < 64; d += 4) {
            s0 += qr[d]     * kr[d];
            s1 += qr[d + 1] * kr[d + 1];
            s2 += qr[d + 2] * kr[d + 2];
            s3 += qr[d + 3] * kr[d + 3];
        }
        Ss[i * 71 + j] = (s0 + s1) + (s2 + s3);
    }
    __syncthreads();
    if (tid < L_) {
        float mx = -1e30f;
        for (int j = 0; j < L_; j++) mx = fmaxf(mx, Ss[tid * 71 + j]);
        float sm = 0.f;
        for (int j = 0; j < L_; j++) { float e = expf(Ss[tid * 71 + j] - mx); Ss[tid * 71 + j] = e; sm += e; }
        float inv = 1.f / sm;
        for (int j = 0; j < L_; j++) Ss[tid * 71 + j] *= inv;
    }
    for (int idx = tid; idx < L_ * DK_; idx += 256) {
        int i = idx >> 6, d = idx & 63;
        ks[i * 65 + d] = v[base + (long)i * H_ + d];
    }
    __syncthreads();
    for (int idx = tid; idx < L_ * DK_; idx += 256) {
        int i = idx >> 6, d = idx & 63;
        const float* sr = Ss + i * 71;
        float s0 = 0.f, s1 = 0.f;
        int j = 0;
        for (; j + 1 < L_; j += 2) {
            s0 += sr[j]     * ks[j * 65 + d];
            s1 += sr[j + 1] * ks[(j + 1) * 65 + d];
        }
        float s = s0 + s1 + sr[70] * ks[70 * 65 + d];
        ushort_t hh = f2bf_rne(s);
        float hf = __uint_as_float(((unsigned)hh) << 16);
        long o = base + (long)i * H_ + d;
        ctxH[o] = hh;
        ctxL[o] = f2bf_rne(s - hf);
    }
}

// Embedding -> bf16 hi/lo planes
__global__ __launch_bounds__(256) void embed_kernel(
    const int* __restrict__ story, const int* __restrict__ query,
    const float* __restrict__ emb, const float* __restrict__ mask,
    ushort_t* __restrict__ xH, ushort_t* __restrict__ xL)
{
    __shared__ int idx[11];
    const int row = blockIdx.x;
    const int b = row / 71, m = row % 71;
    const int tid = threadIdx.x;
    if (tid < 11)
        idx[tid] = (m < 70) ? story[((long)b * 70 + m) * 11 + tid]
                            : query[(long)b * 11 + tid];
    __syncthreads();
    for (int c = tid; c < H_; c += 256) {
        float acc = 0.f;
        #pragma unroll
        for (int s = 0; s < 11; s++)
            acc += emb[(long)idx[s] * H_ + c] * mask[s * H_ + c];
        ushort_t h = f2bf_rne(acc);
        float hf = __uint_as_float(((unsigned)h) << 16);
        long o = (long)row * H_ + c;
        xH[o] = h;
        xL[o] = f2bf_rne(acc - hf);
    }
}

// transpose + split fp32 [R,C] -> bf16 hi/lo planes [C,R]
__global__ __launch_bounds__(256) void wsplitT_kernel(
    const float* __restrict__ in, ushort_t* __restrict__ hi, ushort_t* __restrict__ lo,
    int R, int C)
{
    long i = (long)blockIdx.x * 256 + threadIdx.x;
    if (i < (long)R * C) {
        int r = (int)(i / C), c = (int)(i % C);
        float f = in[i];
        ushort_t h = f2bf_rne(f);
        float hf = __uint_as_float(((unsigned)h) << 16);
        hi[(long)c * R + r] = h;
        lo[(long)c * R + r] = f2bf_rne(f - hf);
    }
}

// conv weight gather+split: plane[n*(3C) + d*C + c] = w[(n*C + c)*3 + d]
__global__ __launch_bounds__(256) void convw_split_kernel(
    const float* __restrict__ w, ushort_t* __restrict__ hi, ushort_t* __restrict__ lo,
    int N, int C)
{
    long i = (long)blockIdx.x * 256 + threadIdx.x;
    if (i < (long)N * C * 3) {
        int n = (int)(i / (3 * C));
        int r = (int)(i % (3 * C));
        int d = r / C, c = r % C;
        float f = w[((long)n * C + c) * 3 + d];
        ushort_t h = f2bf_rne(f);
        float hf = __uint_as_float(((unsigned)h) << 16);
        hi[i] = h;
        lo[i] = f2bf_rne(f - hf);
    }
}

// plain split: emb [V,E] -> hi/lo planes same layout
__global__ __launch_bounds__(256) void esplit_kernel(
    const float* __restrict__ in, ushort_t* __restrict__ hi, ushort_t* __restrict__ lo,
    long n)
{
    long i = (long)blockIdx.x * 256 + threadIdx.x;
    if (i < n) {
        float f = in[i];
        ushort_t h = f2bf_rne(f);
        float hf = __uint_as_float(((unsigned)h) << 16);
        hi[i] = h;
        lo[i] = f2bf_rne(f - hf);
    }
}

__global__ __launch_bounds__(256) void zero_f32(float* __restrict__ p, long n)
{
    long i = (long)blockIdx.x * 256 + threadIdx.x;
    if (i < n) p[i] = 0.f;
}

// pooled[b,c] = (sum_l prev[b,l,c]) / 71 -> bf16 hi/lo planes
__global__ __launch_bounds__(256) void pooled_kernel(
    const float* __restrict__ prev, ushort_t* __restrict__ pH, ushort_t* __restrict__ pL)
{
    int i = blockIdx.x * 256 + threadIdx.x;   // [0, 256*512)
    int b = i >> 9, c = i & 511;
    float s = 0.f;
    for (int l = 0; l < L_; l++) s += prev[((long)b * L_ + l) * H_ + c];
    float p = s / 71.0f;
    ushort_t h = f2bf_rne(p);
    float hf = __uint_as_float(((unsigned)h) << 16);
    pH[i] = h;
    pL[i] = f2bf_rne(p - hf);
}

__global__ __launch_bounds__(256) void softmax_kernel(
    const float* __restrict__ ah, float* __restrict__ out)
{
    __shared__ float red[256];
    const int b = blockIdx.x, tid = threadIdx.x;
    const float* a = ah + (long)b * V_;
    float mx = -1e30f;
    for (int i = tid; i < V_; i += 256) mx = fmaxf(mx, a[i]);
    red[tid] = mx; __syncthreads();
    for (int o = 128; o; o >>= 1) { if (tid < o) red[tid] = fmaxf(red[tid], red[tid + o]); __syncthreads(); }
    mx = red[0]; __syncthreads();
    float s = 0.f;
    for (int i = tid; i < V_; i += 256) s += expf(a[i] - mx);
    red[tid] = s; __syncthreads();
    for (int o = 128; o; o >>= 1) { if (tid < o) red[tid] += red[tid + o]; __syncthreads(); }
    float inv = 1.f / red[0];
    float* o_ = out + (long)b * V_;
    for (int i = tid; i < V_; i += 256) o_[i] = expf(a[i] - mx) * inv;
}

__global__ __launch_bounds__(256) void tails_kernel(
    const float* __restrict__ rem, const float* __restrict__ nu, float* __restrict__ out)
{
    int i = blockIdx.x * 256 + threadIdx.x;
    if (i < M_) {
        out[i] = rem[i];
        out[M_ + i] = nu[i];
    }
}

// ---------------------------------------------------------------------------
extern "C" void kernel_launch(void* const* d_in, const int* in_sizes, int n_in,
                              void* d_out, int out_size, void* d_ws, size_t ws_size,
                              hipStream_t stream)
{
    const int*   story  = (const int*)d_in[0];
    const int*   query  = (const int*)d_in[1];
    const float* emb    = (const float*)d_in[2];
    const float* mask_p = (const float*)d_in[3];
    const float* proj_w = (const float*)d_in[4];
    const float* ln1_g  = (const float*)d_in[5];
    const float* ln1_b  = (const float*)d_in[6];
    const float* wq     = (const float*)d_in[7];
    const float* wk     = (const float*)d_in[8];
    const float* wv     = (const float*)d_in[9];
    const float* wo     = (const float*)d_in[10];
    const float* c1_w   = (const float*)d_in[11];
    const float* c1_b   = (const float*)d_in[12];
    const float* c2_w   = (const float*)d_in[13];
    const float* c2_b   = (const float*)d_in[14];
    const float* ln2_g  = (const float*)d_in[15];
    const float* ln2_b  = (const float*)d_in[16];
    const float* p_w    = (const float*)d_in[17];
    const float* p_b    = (const float*)d_in[18];
    const float* out_b  = (const float*)d_in[19];
    float* outp = (float*)d_out;

    char* wsb = (char*)d_ws;
    size_t off = 0;
    auto alloc = [&](size_t bytes) -> void* {
        void* p = wsb + off;
        off = (off + bytes + 255) & ~(size_t)255;
        return p;
    };
    const long ROWE = (long)M_ * H_;             // 9,306,112 elements

    float* trunkF = (float*)alloc(ROWE * 4);
    float* prevF  = (float*)alloc(ROWE * 4);
    char*  poolC  = (char*)alloc(4L * ROWE * 4); // 148.9 MB multi-purpose pool
    float* hpF    = (float*)alloc((long)M_ * 4 * 4 + 64);
    float* remF   = hpF + M_;
    float* nuF    = hpF + 2 * M_;
    float* uwF    = hpF + 3 * M_;
    int*   flags  = (int*)(hpF + 4 * M_);
    ushort_t* zpg   = (ushort_t*)alloc(256);     // zero page for conv edge chunks
    ushort_t* projH = (ushort_t*)alloc((long)H_ * H_ * 2);
    ushort_t* projL = (ushort_t*)alloc((long)H_ * H_ * 2);
    ushort_t* wqH   = (ushort_t*)alloc((long)H_ * H_ * 2);
    ushort_t* wqL   = (ushort_t*)alloc((long)H_ * H_ * 2);
    ushort_t* wkH   = (ushort_t*)alloc((long)H_ * H_ * 2);
    ushort_t* wkL   = (ushort_t*)alloc((long)H_ * H_ * 2);
    ushort_t* wvH   = (ushort_t*)alloc((long)H_ * H_ * 2);
    ushort_t* wvL   = (ushort_t*)alloc((long)H_ * H_ * 2);
    ushort_t* woH   = (ushort_t*)alloc((long)H_ * H_ * 2);
    ushort_t* woL   = (ushort_t*)alloc((long)H_ * H_ * 2);
    ushort_t* W1H   = (ushort_t*)alloc((long)FS_ * 3 * H_ * 2);
    ushort_t* W1L   = (ushort_t*)alloc((long)FS_ * 3 * H_ * 2);
    ushort_t* W2H   = (ushort_t*)alloc((long)H_ * 3 * FS_ * 2);
    ushort_t* W2L   = (ushort_t*)alloc((long)H_ * 3 * FS_ * 2);
    ushort_t* pooledH = (ushort_t*)alloc((long)B_ * H_ * 2);
    ushort_t* pooledL = (ushort_t*)alloc((long)B_ * H_ * 2);
    float* Ttab     = (float*)alloc((long)L_ * H_ * 4);
    float* Ptab     = (float*)alloc(6L * H_ * 4);

    // pool aliases (phases disjoint in time):
    //   phase A (qkv+attn+wo): xnH|xnL (ctx reuses) + qb + kb + vb
    //   phase B (convs):       xn2H|xn2L + y1H|y1L (half)
    //   pre-loop: xembH|xembL ; post-loop: embH|embL
    ushort_t* xnH = (ushort_t*)poolC;
    ushort_t* xnL = xnH + ROWE;
    float* qbF = (float*)(poolC + ROWE * 4);
    float* kbF = qbF + ROWE;
    float* vbF = qbF + 2 * ROWE;
    ushort_t* ctxH = xnH;
    ushort_t* ctxL = xnL;
    ushort_t* xn2H = (ushort_t*)poolC;
    ushort_t* xn2L = xn2H + ROWE;
    ushort_t* y1H  = (ushort_t*)(poolC + ROWE * 4);
    ushort_t* y1L  = y1H + (long)MH_ * FS_;
    ushort_t* xembH = (ushort_t*)poolC;
    ushort_t* xembL = xembH + ROWE;
    ushort_t* embH = (ushort_t*)poolC;
    ushort_t* embL = embH + (long)V_ * H_;

    dim3 blk(256);

    // --- init (ws re-poisoned every call) ---
    zero_f32<<<dim3((unsigned)((ROWE + 255) / 256)), blk, 0, stream>>>(prevF, ROWE);
    zero_f32<<<dim3((3 * M_ + 255) / 256), blk, 0, stream>>>(hpF, 3 * M_);
    zero_f32<<<dim3(1), blk, 0, stream>>>((float*)flags, 16);
    zero_f32<<<dim3(1), blk, 0, stream>>>((float*)zpg, 64);
    sig_prep<<<dim3(154), blk, 0, stream>>>(Ttab, Ptab);

    // --- weight prep: transpose + hi/lo split ---
    wsplitT_kernel<<<dim3(1024), blk, 0, stream>>>(proj_w, projH, projL, H_, H_);
    wsplitT_kernel<<<dim3(1024), blk, 0, stream>>>(wq, wqH, wqL, H_, H_);
    wsplitT_kernel<<<dim3(1024), blk, 0, stream>>>(wk, wkH, wkL, H_, H_);
    wsplitT_kernel<<<dim3(1024), blk, 0, stream>>>(wv, wvH, wvL, H_, H_);
    wsplitT_kernel<<<dim3(1024), blk, 0, stream>>>(wo, woH, woL, H_, H_);
    convw_split_kernel<<<dim3(12288), blk, 0, stream>>>(c1_w, W1H, W1L, FS_, H_);
    convw_split_kernel<<<dim3(12288), blk, 0, stream>>>(c2_w, W2H, W2L, H_, FS_);

    // --- embedding + input projection ---
    embed_kernel<<<dim3(M_), blk, 0, stream>>>(story, query, emb, mask_p, xembH, xembL);
    gemm_s<<<dim3(H_ / 128, M_ / 128), blk, 0, stream>>>(
        xembH, xembL, H_, 0, 0, 0, projH, projL, H_, H_,
        nullptr, nullptr, 1.f, 0, 0, 0, trunkF, nullptr, nullptr, nullptr, nullptr, zpg);

    // --- ACT loop: 6 steps with faithful any()-gate ---
    for (int t = 0; t < 6; t++) {
        gate_kernel<<<dim3(M_ / 256), blk, 0, stream>>>(hpF, nuF, flags + t);
        s_pr_kernel<<<dim3(M_ / 4), blk, 0, stream>>>(trunkF, Ttab, Ptab, p_w, p_b,
                                                      hpF, remF, nuF, uwF, flags + t, t);
        ln_kernel<<<dim3(M_ / 4), blk, 0, stream>>>(trunkF, ln1_g, ln1_b, xnH, xnL);
        gemm_s<<<dim3(H_ / 128, M_ / 128), blk, 0, stream>>>(
            xnH, xnL, H_, 0, 0, 0, wqH, wqL, H_, H_,
            nullptr, nullptr, 0.125f, 0, 0, 0, qbF, nullptr, nullptr, nullptr, nullptr, zpg);
        gemm_s<<<dim3(H_ / 128, M_ / 128), blk, 0, stream>>>(
            xnH, xnL, H_, 0, 0, 0, wkH, wkL, H_, H_,
            nullptr, nullptr, 1.f, 0, 0, 0, kbF, nullptr, nullptr, nullptr, nullptr, zpg);
        gemm_s<<<dim3(H_ / 128, M_ / 128), blk, 0, stream>>>(
            xnH, xnL, H_, 0, 0, 0, wvH, wvL, H_, H_,
            nullptr, nullptr, 1.f, 0, 0, 0, vbF, nullptr, nullptr, nullptr, nullptr, zpg);
        attn_kernel<<<dim3(B_ * NH_), blk, 0, stream>>>(qbF, kbF, vbF, ctxH, ctxL);
        gemm_s<<<dim3(H_ / 128, M_ / 128), blk, 0, stream>>>(
            ctxH, ctxL, H_, 0, 0, 0, woH, woL, H_, H_,
            nullptr, trunkF, 1.f, 0, 0, 0, trunkF, nullptr, nullptr, nullptr, nullptr, zpg);
        ln_kernel<<<dim3(M_ / 4), blk, 0, stream>>>(trunkF, ln2_g, ln2_b, xn2H, xn2L);
        for (int half = 0; half < 2; half++) {
            int ro = half * MH_;
            gemm_s<<<dim3(FS_ / 128, MH_ / 128), blk, 0, stream>>>(
                xn2H, xn2L, H_, 1, ro, ro, W1H, W1L, FS_, 3 * H_,
                c1_b, nullptr, 1.f, 1, 0, 2, nullptr, y1H, y1L, nullptr, nullptr, zpg);
            gemm_s<<<dim3(H_ / 128, MH_ / 128), blk, 0, stream>>>(
                y1H, y1L, FS_, 1, 0, ro, W2H, W2L, H_, 3 * FS_,
                c2_b, trunkF, 1.f, 0, ro, 1, trunkF, nullptr, nullptr, prevF, uwF, zpg);
        }
    }

    // --- output head ---
    pooled_kernel<<<dim3(B_ * H_ / 256), blk, 0, stream>>>(prevF, pooledH, pooledL);
    esplit_kernel<<<dim3(64000), blk, 0, stream>>>(emb, embH, embL, (long)V_ * H_);
    gemm_s<<<dim3(V_ / 128, B_ / 128), blk, 0, stream>>>(
        pooledH, pooledL, H_, 0, 0, 0, embH, embL, V_, H_,
        out_b, nullptr, 1.f, 0, 0, 0, outp, nullptr, nullptr, nullptr, nullptr, zpg);
    softmax_kernel<<<dim3(B_), blk, 0, stream>>>(outp, outp + (long)B_ * V_);
    tails_kernel<<<dim3((M_ + 255) / 256), blk, 0, stream>>>(remF, nuF, outp + 2L * B_ * V_);
}

// Round 3
// 10958.200 us; speedup vs baseline: 1.2511x; 1.2511x over previous
//
#include <hip/hip_runtime.h>
#include <hip/hip_bf16.h>
#include <math.h>

// ---------------------------------------------------------------------------
// BabiUTransformer (Universal Transformer + ACT) on gfx950.  All float I/O fp32.
// GEMMs: split-precision bf16 MFMA (hh+lh+hl, err ~2^-18 rel). Activations are
// pre-split into hi/lo bf16 planes by their PRODUCER kernels.
// GEMM v4 (this round): single-buffered 2-barrier loop (r2's explicit dbuf
// regressed: compiler can't disambiguate buf[cur] ds_reads from buf[cur^1]
// global_load_lds writes -> inserts its own vmcnt(0) pre-compute).  The lever
// is OCCUPANCY: tiles are TM=128 x TN in {64,128} so every GEMM dispatch has
// >=1000 blocks (>=3.9 blocks/CU); conv2 (K=6144, was 284 blocks) is split-K=2
// with fp32 partials + reduce kernel; q/k/v are fused into one N=1536 GEMM
// (1/8 q-scale folded into the wq weight split -- bit-exact, pow2 scaling).
// LDS: [group16][kchunk8][row16] subtiles, fragment ds_read_b128s are
// 1KiB-contiguous per wave (0 bank conflicts, verified r1); lane permutation
// carried on the per-lane GLOBAL source address of global_load_lds (width 16).
// Conv edge zero-fill via per-lane redirect of the source pointer to a
// zeroed 256B page (numerically identical to register zero-fill).
// Attention: LDS stride padded 64->65 (kills 64-way bank conflict).
// ACT any()-gate via per-step device flag (ballot-reduced).
// ---------------------------------------------------------------------------

typedef unsigned short ushort_t;
using short8  = __attribute__((ext_vector_type(8))) short;
using floatx4 = __attribute__((ext_vector_type(4))) float;

#define B_   256
#define L_   71
#define H_   512
#define M_   (B_*L_)      // 18176 rows (142 x 128); half = 9088 (71 x 128)
#define MH_  9088
#define FS_  2048
#define V_   32000
#define NH_  8
#define DK_  64

__device__ inline ushort_t f2bf_rne(float f) {
    unsigned u = __float_as_uint(f);
    return (ushort_t)((u + 0x7FFFu + ((u >> 16) & 1u)) >> 16);
}

// async global->LDS, 16B per lane. LDS dest must be wave-uniform base
// (hardware writes base + lane*16); global src is per-lane.
__device__ __forceinline__ void gload16(const void* g, void* l)
{
    __builtin_amdgcn_global_load_lds(
        (__attribute__((address_space(1))) unsigned int*)(g),
        (__attribute__((address_space(3))) unsigned int*)(l),
        16, 0, 0);
}

// ---------------------------------------------------------------------------
// Split GEMM: C[M,N] = alpha*(A @ B) (+bias)(+residual)(relu)
// A pre-split hi/lo bf16 planes [rows, lda]. B hi/lo planes [N,K] row-major.
// conv=1: row m's 3C window starts at A row (am+rowA-1); k-chunk d==0 invalid
//   at l==0, d==2 invalid at l==70 (zero via zpg redirect). l from (am+rowG)%71.
// outMode: 0 = f32 out; 1 = f32 + fused prev-update; 2 = bf16 hi/lo out;
//          3 = raw fp32 partial to Cout + blockIdx.z*partStride (split-K).
// K param is the PER-CHUNK k-length; kBeg = blockIdx.z*K (gridDim.z chunks).
// Tile TM=128 x TN (64 or 128), BK=32, 4 waves, 256 threads.
//   TN=128: waves 2x2, each 64x64 (4x4 frags).  TN=64: waves 4x1 along M,
//   each 32x64 (2x4 frags).
// ---------------------------------------------------------------------------
template<int TN>
__global__ __launch_bounds__(256) void gemm_s(
    const ushort_t* __restrict__ AH, const ushort_t* __restrict__ AL,
    int lda, int conv, int rowA, int rowG,
    const ushort_t* __restrict__ Bh, const ushort_t* __restrict__ Bl,
    int N, int K,
    const float* __restrict__ bias, const float* residual,
    float alpha, int relu, int rowC, int outMode,
    float* Cout, ushort_t* CoutH, ushort_t* CoutL,
    float* prev, const float* __restrict__ uw,
    long partStride, const ushort_t* __restrict__ zpg)
{
    constexpr int AF = (TN == 128) ? 4 : 2;   // a-frags per wave
    // A: 8 groups x [4kc x 16row x 8shorts] = 4096 shorts (8KB) per plane
    __shared__ __attribute__((aligned(16))) short Ahs[4096], Als[4096];
    __shared__ __attribute__((aligned(16))) short Bhs[TN * 32], Bls[TN * 32];

    const int tid  = threadIdx.x;
    const int w    = tid >> 6, lane = tid & 63;
    const int bm = blockIdx.y << 7, bn = blockIdx.x * TN;

    // ---- staging setup ----
    const int srow = lane & 15;        // row within 16-row group
    const int skc  = lane >> 4;        // k-chunk (8 shorts) 0..3
    const int ra0  = w * 16 + srow;    // A tile rows this thread stages
    const int ra1  = ra0 + 64;
    const int am0  = bm + ra0, am1 = bm + ra1;
    const int ash  = conv ? (rowA - 1) : rowA;
    const ushort_t* pAh0 = AH + (long)(am0 + ash) * lda + skc * 8;
    const ushort_t* pAl0 = AL + (long)(am0 + ash) * lda + skc * 8;
    const ushort_t* pAh1 = AH + (long)(am1 + ash) * lda + skc * 8;
    const ushort_t* pAl1 = AL + (long)(am1 + ash) * lda + skc * 8;
    int l0 = 0, l1 = 0;
    if (conv) { l0 = (am0 + rowG) % 71; l1 = (am1 + rowG) % 71; }
    const ushort_t* pBh0 = Bh + (long)(bn + ra0) * K;   // note: K==lda of B rows? no: B is [N,Kfull]
    // B row stride is the FULL K of the B matrix. For split-K the chunk length
    // K may be < full K; B rows are indexed with the full stride via ldb:
    // we pass B pre-offset is not possible (kBeg varies per block). Use ldbK:
    // for all current calls, B's row stride equals the full K of the GEMM,
    // which is K * gridDim.z.  Compute it:
    const long ldb = (long)K * gridDim.z;
    pBh0 = Bh + (long)(bn + ra0) * ldb + skc * 8;
    const ushort_t* pBl0 = Bl + (long)(bn + ra0) * ldb + skc * 8;
    const ushort_t* pBh1 = (TN == 128) ? (Bh + (long)(bn + ra1) * ldb + skc * 8) : nullptr;
    const ushort_t* pBl1 = (TN == 128) ? (Bl + (long)(bn + ra1) * ldb + skc * 8) : nullptr;

    // ---- fragment read offsets (wave reads 1KiB contiguous, conflict-free) --
    const int quad = lane >> 4, mr = lane & 15;
    const int wrM   = (TN == 128) ? ((w >> 1) << 6) : (w << 5);
    const int wcN   = (TN == 128) ? ((w & 1) << 6) : 0;
    const int agrp0 = (TN == 128) ? ((w >> 1) << 2) : (w << 1);
    const int bgrp0 = (TN == 128) ? ((w & 1) << 2) : 0;
    const int foff  = quad * 128 + mr * 8;

    floatx4 acc[AF][4] = {};

    const int kBeg = blockIdx.z * K;
    const int kEnd = kBeg + K;

    for (int k0 = kBeg; k0 < kEnd; k0 += 32) {
        const ushort_t* sA0h = pAh0 + k0;
        const ushort_t* sA0l = pAl0 + k0;
        const ushort_t* sA1h = pAh1 + k0;
        const ushort_t* sA1l = pAl1 + k0;
        if (conv) {
            // lda is a multiple of 32 -> d uniform across the K-step
            const int d = (k0 >= lda) ? ((k0 >= 2 * lda) ? 2 : 1) : 0;
            if ((l0 == 0 && d == 0) || (l0 == 70 && d == 2)) { sA0h = zpg; sA0l = zpg; }
            if ((l1 == 0 && d == 0) || (l1 == 70 && d == 2)) { sA1h = zpg; sA1l = zpg; }
        }
        __syncthreads();   // previous step's ds_reads done before overwrite
        gload16(sA0h, Ahs + w * 512);
        gload16(sA1h, Ahs + (w + 4) * 512);
        gload16(sA0l, Als + w * 512);
        gload16(sA1l, Als + (w + 4) * 512);
        if constexpr (TN == 128) {
            gload16(pBh0 + k0, Bhs + w * 512);
            gload16(pBh1 + k0, Bhs + (w + 4) * 512);
            gload16(pBl0 + k0, Bls + w * 512);
            gload16(pBl1 + k0, Bls + (w + 4) * 512);
        } else {
            gload16(pBh0 + k0, Bhs + w * 512);
            gload16(pBl0 + k0, Bls + w * 512);
        }
        __syncthreads();   // loads landed (compiler drains vmcnt here)

        short8 ah[AF], al[AF], bh[4], bl[4];
        #pragma unroll
        for (int i = 0; i < AF; i++) {
            ah[i] = *(const short8*)(Ahs + (agrp0 + i) * 512 + foff);
            al[i] = *(const short8*)(Als + (agrp0 + i) * 512 + foff);
        }
        #pragma unroll
        for (int j = 0; j < 4; j++) {
            bh[j] = *(const short8*)(Bhs + (bgrp0 + j) * 512 + foff);
            bl[j] = *(const short8*)(Bls + (bgrp0 + j) * 512 + foff);
        }
        #pragma unroll
        for (int i = 0; i < AF; i++)
        #pragma unroll
        for (int j = 0; j < 4; j++) {
            acc[i][j] = __builtin_amdgcn_mfma_f32_16x16x32_bf16(ah[i], bh[j], acc[i][j], 0, 0, 0);
            acc[i][j] = __builtin_amdgcn_mfma_f32_16x16x32_bf16(al[i], bh[j], acc[i][j], 0, 0, 0);
            acc[i][j] = __builtin_amdgcn_mfma_f32_16x16x32_bf16(ah[i], bl[j], acc[i][j], 0, 0, 0);
        }
    }

    // C/D layout: col = lane&15, row = quad*4 + r  [verified m89/m91]
    #pragma unroll
    for (int j = 0; j < 4; j++) {
        const int gcol = bn + wcN + j * 16 + mr;
        const float bv = bias ? bias[gcol] : 0.f;
        #pragma unroll
        for (int i = 0; i < AF; i++) {
            #pragma unroll
            for (int r = 0; r < 4; r++) {
                const int grow = bm + wrM + i * 16 + quad * 4 + r;
                if (outMode == 3) {
                    Cout[(long)blockIdx.z * partStride + (long)grow * N + gcol] =
                        acc[i][j][r] * alpha;
                    continue;
                }
                const long crow = (long)grow + rowC;
                float v = acc[i][j][r] * alpha + bv;
                if (residual) v += residual[crow * N + gcol];
                if (relu) v = fmaxf(v, 0.f);
                const long cidx = crow * (long)N + gcol;
                if (outMode == 2) {
                    ushort_t h = f2bf_rne(v);
                    float hf = __uint_as_float(((unsigned)h) << 16);
                    CoutH[cidx] = h;
                    CoutL[cidx] = f2bf_rne(v - hf);
                } else {
                    Cout[cidx] = v;
                    if (outMode == 1) {
                        float u = uw[crow];
                        prev[cidx] = v * u + prev[cidx] * (1.f - u);
                    }
                }
            }
        }
    }
}

// split-K=2 reduce for conv2: v = p0+p1+bias+trunk; trunk=v; prev update.
__global__ __launch_bounds__(256) void conv2_reduce(
    const float* __restrict__ part, long partStride,
    const float* __restrict__ bias, float* __restrict__ trunk,
    float* __restrict__ prev, const float* __restrict__ uw, int rowC)
{
    const long n4 = (long)MH_ * H_ / 4;
    long i4 = (long)blockIdx.x * 256 + threadIdx.x;
    if (i4 >= n4) return;
    const long row  = i4 >> 7;            // 0..9087 (128 float4 per row)
    const float4 p0 = ((const float4*)part)[i4];
    const float4 p1 = ((const float4*)(part + partStride))[i4];
    const float4 b4 = ((const float4*)bias)[i4 & 127];
    const long  ti  = (long)rowC * 128 + i4;
    float4 tv = ((const float4*)trunk)[ti];
    float4 v;
    v.x = p0.x + p1.x + b4.x + tv.x;
    v.y = p0.y + p1.y + b4.y + tv.y;
    v.z = p0.z + p1.z + b4.z + tv.z;
    v.w = p0.w + p1.w + b4.w + tv.w;
    ((float4*)trunk)[ti] = v;
    const float u = uw[rowC + row];
    float4 pv = ((const float4*)prev)[ti];
    pv.x = v.x * u + pv.x * (1.f - u);
    pv.y = v.y * u + pv.y * (1.f - u);
    pv.z = v.z * u + pv.z * (1.f - u);
    pv.w = v.w * u + pv.w * (1.f - u);
    ((float4*)prev)[ti] = pv;
}

// Timing-signal tables, float32 math (matches numpy float32 exp/sin chain).
__global__ __launch_bounds__(256) void sig_prep(float* __restrict__ T, float* __restrict__ P)
{
    int i = blockIdx.x * 256 + threadIdx.x;
    const int NT = 71 * 512;
    if (i >= NT + 6 * 512) return;
    int pos, c, idx;
    float* dst;
    if (i < NT) { pos = i >> 9; c = i & 511; dst = T; idx = i; }
    else        { int j = i - NT; pos = j >> 9; c = j & 511; dst = P; idx = j; }
    const float loginc = 0.036119766f;
    int jj = c & 255;
    float inv = expf(-(float)jj * loginc);
    float arg = (float)pos * inv;
    dst[idx] = (c < 256) ? sinf(arg) : cosf(arg);
}

// active-gate: flag |= any(hp<0.9 && nu<6)   (ballot, 1 atomic/wave)
__global__ __launch_bounds__(256) void gate_kernel(
    const float* __restrict__ hp, const float* __restrict__ nu, int* __restrict__ flag)
{
    int i = blockIdx.x * 256 + threadIdx.x;
    bool act = (i < M_) && (hp[i] < 0.9f) && (nu[i] < 6.0f);
    unsigned long long b = __ballot(act);
    if ((threadIdx.x & 63) == 0 && b) atomicOr(flag, 1);
}

// s = state + T[l] + P[t] (in-place); pr = sigmoid(s.p_w+p_b); gated ACT.
__global__ __launch_bounds__(256) void s_pr_kernel(
    float* trunk, const float* __restrict__ Ttab, const float* __restrict__ Ptab,
    const float* __restrict__ p_w, const float* __restrict__ p_b,
    float* __restrict__ hp, float* __restrict__ rem, float* __restrict__ nu,
    float* __restrict__ uw, const int* __restrict__ flag, int t)
{
    const int row  = blockIdx.x * 4 + (threadIdx.x >> 6);
    const int lane = threadIdx.x & 63;
    const int l    = row % 71;
    float dot = 0.f;
    #pragma unroll
    for (int j = 0; j < 8; j++) {
        int c  = lane + 64 * j;
        float sv = trunk[(long)row * H_ + c] + Ttab[l * H_ + c] + Ptab[t * H_ + c];
        trunk[(long)row * H_ + c] = sv;
        dot += sv * p_w[c];
    }
    #pragma unroll
    for (int o = 32; o; o >>= 1) dot += __shfl_xor(dot, o);
    if (lane == 0) {
        if (flag[0]) {
            float pr = 1.f / (1.f + expf(-(dot + p_b[0])));
            float hp0 = hp[row], rem0 = rem[row], nu0 = nu[row];
            float still = (hp0 < 1.0f) ? 1.f : 0.f;
            float tot   = hp0 + pr * still;
            float nh    = ((tot > 0.9f) ? 1.f : 0.f) * still;
            float st2   = ((tot <= 0.9f) ? 1.f : 0.f) * still;
            float hp2   = hp0 + pr * st2;
            float rem2  = rem0 + nh * (1.f - hp2);
            hp2 += nh * rem2;
            hp[row] = hp2; rem[row] = rem2; nu[row] = nu0 + st2 + nh;
            uw[row] = pr * st2 + nh * rem2;
        } else {
            uw[row] = 0.f;
        }
    }
}

// LayerNorm fp32 -> bf16 hi/lo planes.
__global__ __launch_bounds__(256) void ln_kernel(
    const float* __restrict__ X, const float* __restrict__ g,
    const float* __restrict__ bb, ushort_t* __restrict__ outH,
    ushort_t* __restrict__ outL)
{
    const int row  = blockIdx.x * 4 + (threadIdx.x >> 6);
    const int lane = threadIdx.x & 63;
    const float* xr = X + (long)row * H_;
    float v[8];
    float s = 0.f;
    #pragma unroll
    for (int j = 0; j < 8; j++) { v[j] = xr[lane + 64 * j]; s += v[j]; }
    #pragma unroll
    for (int o = 32; o; o >>= 1) s += __shfl_xor(s, o);
    float mean = s * (1.f / 512.f);
    float q = 0.f;
    #pragma unroll
    for (int j = 0; j < 8; j++) { float d = v[j] - mean; q += d * d; }
    #pragma unroll
    for (int o = 32; o; o >>= 1) q += __shfl_xor(q, o);
    float sd  = sqrtf(q * (1.f / 511.f));
    float inv = 1.f / (sd + 1e-6f);
    #pragma unroll
    for (int j = 0; j < 8; j++) {
        int c = lane + 64 * j;
        float val = g[c] * (v[j] - mean) * inv + bb[c];
        ushort_t h = f2bf_rne(val);
        float hf = __uint_as_float(((unsigned)h) << 16);
        long idx = (long)row * H_ + c;
        outH[idx] = h;
        outL[idx] = f2bf_rne(val - hf);
    }
}

// Attention, fp32, LDS stride 65 (conflict-free). One block per (b,h).
// q pre-scaled by 1/8 (folded into wq split). qkv fused [M,1536]:
// q at +0, k at +512, v at +1024. ctx written as bf16 hi/lo planes [M,512].
__global__ __launch_bounds__(256) void attn_kernel(
    const float* __restrict__ qkv, ushort_t* __restrict__ ctxH,
    ushort_t* __restrict__ ctxL)
{
    __shared__ float qs[L_ * 65];
    __shared__ float ks[L_ * 65];   // reused for V
    __shared__ float Ss[L_ * L_];
    const int tid = threadIdx.x;
    const int b = blockIdx.x >> 3, h = blockIdx.x & 7;
    const long qbase = (long)b * L_ * 1536 + h * DK_;
    for (int idx = tid; idx < L_ * DK_; idx += 256) {
        int i = idx >> 6, d = idx & 63;
        qs[i * 65 + d] = qkv[qbase + (long)i * 1536 + d];
        ks[i * 65 + d] = qkv[qbase + 512 + (long)i * 1536 + d];
    }
    __syncthreads();
    for (int idx = tid; idx < L_ * L_; idx += 256) {
        int i = idx / 71, j = idx % 71;
        const float* qr = qs + i * 65;
        const float* kr = ks + j * 65;
        float s0 = 0.f, s1 = 0.f, s2 = 0.f, s3 = 0.f;
        #pragma unroll
        for (int d = 0; d < 64; d += 4) {
            s0 += qr[d]     * kr[d];
            s1 += qr[d + 1] * kr[d + 1];
            s2 += qr[d + 2] * kr[d + 2];
            s3 += qr[d + 3] * kr[d + 3];
        }
        Ss[i * 71 + j] = (s0 + s1) + (s2 + s3);
    }
    __syncthreads();
    if (tid < L_) {
        float mx = -1e30f;
        for (int j = 0; j < L_; j++) mx = fmaxf(mx, Ss[tid * 71 + j]);
        float sm = 0.f;
        for (int j = 0; j < L_; j++) { float e = expf(Ss[tid * 71 + j] - mx); Ss[tid * 71 + j] = e; sm += e; }
        float inv = 1.f / sm;
        for (int j = 0; j < L_; j++) Ss[tid * 71 + j] *= inv;
    }
    for (int idx = tid; idx < L_ * DK_; idx += 256) {
        int i = idx >> 6, d = idx & 63;
        ks[i * 65 + d] = qkv[qbase + 1024 + (long)i * 1536 + d];
    }
    __syncthreads();
    const long obase = (long)b * L_ * H_ + h * DK_;
    for (int idx = tid; idx < L_ * DK_; idx += 256) {
        int i = idx >> 6, d = idx & 63;
        const float* sr = Ss + i * 71;
        float s0 = 0.f, s1 = 0.f;
        int j = 0;
        for (; j + 1 < L_; j += 2) {
            s0 += sr[j]     * ks[j * 65 + d];
            s1 += sr[j + 1] * ks[(j + 1) * 65 + d];
        }
        float s = s0 + s1 + sr[70] * ks[70 * 65 + d];
        ushort_t hh = f2bf_rne(s);
        float hf = __uint_as_float(((unsigned)hh) << 16);
        long o = obase + (long)i * H_ + d;
        ctxH[o] = hh;
        ctxL[o] = f2bf_rne(s - hf);
    }
}

// Embedding -> bf16 hi/lo planes
__global__ __launch_bounds__(256) void embed_kernel(
    const int* __restrict__ story, const int* __restrict__ query,
    const float* __restrict__ emb, const float* __restrict__ mask,
    ushort_t* __restrict__ xH, ushort_t* __restrict__ xL)
{
    __shared__ int idx[11];
    const int row = blockIdx.x;
    const int b = row / 71, m = row % 71;
    const int tid = threadIdx.x;
    if (tid < 11)
        idx[tid] = (m < 70) ? story[((long)b * 70 + m) * 11 + tid]
                            : query[(long)b * 11 + tid];
    __syncthreads();
    for (int c = tid; c < H_; c += 256) {
        float acc = 0.f;
        #pragma unroll
        for (int s = 0; s < 11; s++)
            acc += emb[(long)idx[s] * H_ + c] * mask[s * H_ + c];
        ushort_t h = f2bf_rne(acc);
        float hf = __uint_as_float(((unsigned)h) << 16);
        long o = (long)row * H_ + c;
        xH[o] = h;
        xL[o] = f2bf_rne(acc - hf);
    }
}

// transpose + scale + split fp32 [R,C] -> bf16 hi/lo planes rows rowOff..rowOff+C-1, ld=R
__global__ __launch_bounds__(256) void wsplitT_kernel(
    const float* __restrict__ in, ushort_t* __restrict__ hi, ushort_t* __restrict__ lo,
    int R, int C, int rowOff, float scale)
{
    long i = (long)blockIdx.x * 256 + threadIdx.x;
    if (i < (long)R * C) {
        int r = (int)(i / C), c = (int)(i % C);
        float f = in[i] * scale;
        ushort_t h = f2bf_rne(f);
        float hf = __uint_as_float(((unsigned)h) << 16);
        hi[(long)(c + rowOff) * R + r] = h;
        lo[(long)(c + rowOff) * R + r] = f2bf_rne(f - hf);
    }
}

// conv weight gather+split: plane[n*(3C) + d*C + c] = w[(n*C + c)*3 + d]
__global__ __launch_bounds__(256) void convw_split_kernel(
    const float* __restrict__ w, ushort_t* __restrict__ hi, ushort_t* __restrict__ lo,
    int N, int C)
{
    long i = (long)blockIdx.x * 256 + threadIdx.x;
    if (i < (long)N * C * 3) {
        int n = (int)(i / (3 * C));
        int r = (int)(i % (3 * C));
        int d = r / C, c = r % C;
        float f = w[((long)n * C + c) * 3 + d];
        ushort_t h = f2bf_rne(f);
        float hf = __uint_as_float(((unsigned)h) << 16);
        hi[i] = h;
        lo[i] = f2bf_rne(f - hf);
    }
}

// plain split: emb [V,E] -> hi/lo planes same layout
__global__ __launch_bounds__(256) void esplit_kernel(
    const float* __restrict__ in, ushort_t* __restrict__ hi, ushort_t* __restrict__ lo,
    long n)
{
    long i = (long)blockIdx.x * 256 + threadIdx.x;
    if (i < n) {
        float f = in[i];
        ushort_t h = f2bf_rne(f);
        float hf = __uint_as_float(((unsigned)h) << 16);
        hi[i] = h;
        lo[i] = f2bf_rne(f - hf);
    }
}

__global__ __launch_bounds__(256) void zero_f32(float* __restrict__ p, long n)
{
    long i = (long)blockIdx.x * 256 + threadIdx.x;
    if (i < n) p[i] = 0.f;
}

// pooled[b,c] = (sum_l prev[b,l,c]) / 71 -> bf16 hi/lo planes
__global__ __launch_bounds__(256) void pooled_kernel(
    const float* __restrict__ prev, ushort_t* __restrict__ pH, ushort_t* __restrict__ pL)
{
    int i = blockIdx.x * 256 + threadIdx.x;   // [0, 256*512)
    int b = i >> 9, c = i & 511;
    float s = 0.f;
    for (int l = 0; l < L_; l++) s += prev[((long)b * L_ + l) * H_ + c];
    float p = s / 71.0f;
    ushort_t h = f2bf_rne(p);
    float hf = __uint_as_float(((unsigned)h) << 16);
    pH[i] = h;
    pL[i] = f2bf_rne(p - hf);
}

__global__ __launch_bounds__(256) void softmax_kernel(
    const float* __restrict__ ah, float* __restrict__ out)
{
    __shared__ float red[256];
    const int b = blockIdx.x, tid = threadIdx.x;
    const float* a = ah + (long)b * V_;
    float mx = -1e30f;
    for (int i = tid; i < V_; i += 256) mx = fmaxf(mx, a[i]);
    red[tid] = mx; __syncthreads();
    for (int o = 128; o; o >>= 1) { if (tid < o) red[tid] = fmaxf(red[tid], red[tid + o]); __syncthreads(); }
    mx = red[0]; __syncthreads();
    float s = 0.f;
    for (int i = tid; i < V_; i += 256) s += expf(a[i] - mx);
    red[tid] = s; __syncthreads();
    for (int o = 128; o; o >>= 1) { if (tid < o) red[tid] += red[tid + o]; __syncthreads(); }
    float inv = 1.f / red[0];
    float* o_ = out + (long)b * V_;
    for (int i = tid; i < V_; i += 256) o_[i] = expf(a[i] - mx) * inv;
}

__global__ __launch_bounds__(256) void tails_kernel(
    const float* __restrict__ rem, const float* __restrict__ nu, float* __restrict__ out)
{
    int i = blockIdx.x * 256 + threadIdx.x;
    if (i < M_) {
        out[i] = rem[i];
        out[M_ + i] = nu[i];
    }
}

// ---------------------------------------------------------------------------
extern "C" void kernel_launch(void* const* d_in, const int* in_sizes, int n_in,
                              void* d_out, int out_size, void* d_ws, size_t ws_size,
                              hipStream_t stream)
{
    const int*   story  = (const int*)d_in[0];
    const int*   query  = (const int*)d_in[1];
    const float* emb    = (const float*)d_in[2];
    const float* mask_p = (const float*)d_in[3];
    const float* proj_w = (const float*)d_in[4];
    const float* ln1_g  = (const float*)d_in[5];
    const float* ln1_b  = (const float*)d_in[6];
    const float* wq     = (const float*)d_in[7];
    const float* wk     = (const float*)d_in[8];
    const float* wv     = (const float*)d_in[9];
    const float* wo     = (const float*)d_in[10];
    const float* c1_w   = (const float*)d_in[11];
    const float* c1_b   = (const float*)d_in[12];
    const float* c2_w   = (const float*)d_in[13];
    const float* c2_b   = (const float*)d_in[14];
    const float* ln2_g  = (const float*)d_in[15];
    const float* ln2_b  = (const float*)d_in[16];
    const float* p_w    = (const float*)d_in[17];
    const float* p_b    = (const float*)d_in[18];
    const float* out_b  = (const float*)d_in[19];
    float* outp = (float*)d_out;

    char* wsb = (char*)d_ws;
    size_t off = 0;
    auto alloc = [&](size_t bytes) -> void* {
        void* p = wsb + off;
        off = (off + bytes + 255) & ~(size_t)255;
        return p;
    };
    const long ROWE = (long)M_ * H_;             // 9,306,112 elements

    float* trunkF = (float*)alloc(ROWE * 4);
    float* prevF  = (float*)alloc(ROWE * 4);
    char*  poolC  = (char*)alloc(4L * ROWE * 4); // 148.9 MB multi-purpose pool
    float* hpF    = (float*)alloc((long)M_ * 4 * 4 + 64);
    float* remF   = hpF + M_;
    float* nuF    = hpF + 2 * M_;
    float* uwF    = hpF + 3 * M_;
    int*   flags  = (int*)(hpF + 4 * M_);
    ushort_t* zpg   = (ushort_t*)alloc(256);     // zero page for conv edge chunks
    ushort_t* projH = (ushort_t*)alloc((long)H_ * H_ * 2);
    ushort_t* projL = (ushort_t*)alloc((long)H_ * H_ * 2);
    ushort_t* wqkvH = (ushort_t*)alloc((long)3 * H_ * H_ * 2);
    ushort_t* wqkvL = (ushort_t*)alloc((long)3 * H_ * H_ * 2);
    ushort_t* woH   = (ushort_t*)alloc((long)H_ * H_ * 2);
    ushort_t* woL   = (ushort_t*)alloc((long)H_ * H_ * 2);
    ushort_t* W1H   = (ushort_t*)alloc((long)FS_ * 3 * H_ * 2);
    ushort_t* W1L   = (ushort_t*)alloc((long)FS_ * 3 * H_ * 2);
    ushort_t* W2H   = (ushort_t*)alloc((long)H_ * 3 * FS_ * 2);
    ushort_t* W2L   = (ushort_t*)alloc((long)H_ * 3 * FS_ * 2);
    ushort_t* pooledH = (ushort_t*)alloc((long)B_ * H_ * 2);
    ushort_t* pooledL = (ushort_t*)alloc((long)B_ * H_ * 2);
    float* Ttab     = (float*)alloc((long)L_ * H_ * 4);
    float* Ptab     = (float*)alloc(6L * H_ * 4);

    // pool aliases (phases disjoint in time):
    //   phase A (qkv+attn+wo): xnH|xnL (ctx reuses) + qkvF [M,1536] f32
    //   phase B (convs):       xn2H|xn2L + y1H|y1L (half) + partF (split-K)
    //   pre-loop: xembH|xembL ; post-loop: embH|embL
    ushort_t* xnH = (ushort_t*)poolC;
    ushort_t* xnL = xnH + ROWE;
    float* qkvF = (float*)(poolC + ROWE * 4);            // 3*ROWE floats
    ushort_t* ctxH = xnH;
    ushort_t* ctxL = xnL;
    ushort_t* xn2H = (ushort_t*)poolC;
    ushort_t* xn2L = xn2H + ROWE;
    ushort_t* y1H  = (ushort_t*)(poolC + ROWE * 4);
    ushort_t* y1L  = y1H + (long)MH_ * FS_;
    float* partF   = (float*)(poolC + ROWE * 4 + (long)MH_ * FS_ * 4);  // 2 x MH_*H_ f32
    ushort_t* xembH = (ushort_t*)poolC;
    ushort_t* xembL = xembH + ROWE;
    ushort_t* embH = (ushort_t*)poolC;
    ushort_t* embL = embH + (long)V_ * H_;

    dim3 blk(256);

    // --- init (ws re-poisoned every call) ---
    zero_f32<<<dim3((unsigned)((ROWE + 255) / 256)), blk, 0, stream>>>(prevF, ROWE);
    zero_f32<<<dim3((3 * M_ + 255) / 256), blk, 0, stream>>>(hpF, 3 * M_);
    zero_f32<<<dim3(1), blk, 0, stream>>>((float*)flags, 16);
    zero_f32<<<dim3(1), blk, 0, stream>>>((float*)zpg, 64);
    sig_prep<<<dim3(154), blk, 0, stream>>>(Ttab, Ptab);

    // --- weight prep: transpose + hi/lo split (q-scale 1/8 folded, bit-exact) ---
    wsplitT_kernel<<<dim3(1024), blk, 0, stream>>>(proj_w, projH, projL, H_, H_, 0, 1.f);
    wsplitT_kernel<<<dim3(1024), blk, 0, stream>>>(wq, wqkvH, wqkvL, H_, H_, 0, 0.125f);
    wsplitT_kernel<<<dim3(1024), blk, 0, stream>>>(wk, wqkvH, wqkvL, H_, H_, 512, 1.f);
    wsplitT_kernel<<<dim3(1024), blk, 0, stream>>>(wv, wqkvH, wqkvL, H_, H_, 1024, 1.f);
    wsplitT_kernel<<<dim3(1024), blk, 0, stream>>>(wo, woH, woL, H_, H_, 0, 1.f);
    convw_split_kernel<<<dim3(12288), blk, 0, stream>>>(c1_w, W1H, W1L, FS_, H_);
    convw_split_kernel<<<dim3(12288), blk, 0, stream>>>(c2_w, W2H, W2L, H_, FS_);

    // --- embedding + input projection ---
    embed_kernel<<<dim3(M_), blk, 0, stream>>>(story, query, emb, mask_p, xembH, xembL);
    gemm_s<64><<<dim3(H_ / 64, M_ / 128), blk, 0, stream>>>(
        xembH, xembL, H_, 0, 0, 0, projH, projL, H_, H_,
        nullptr, nullptr, 1.f, 0, 0, 0, trunkF, nullptr, nullptr, nullptr, nullptr, 0, zpg);

    // --- ACT loop: 6 steps with faithful any()-gate ---
    for (int t = 0; t < 6; t++) {
        gate_kernel<<<dim3(M_ / 256), blk, 0, stream>>>(hpF, nuF, flags + t);
        s_pr_kernel<<<dim3(M_ / 4), blk, 0, stream>>>(trunkF, Ttab, Ptab, p_w, p_b,
                                                      hpF, remF, nuF, uwF, flags + t, t);
        ln_kernel<<<dim3(M_ / 4), blk, 0, stream>>>(trunkF, ln1_g, ln1_b, xnH, xnL);
        gemm_s<128><<<dim3(1536 / 128, M_ / 128), blk, 0, stream>>>(
            xnH, xnL, H_, 0, 0, 0, wqkvH, wqkvL, 1536, H_,
            nullptr, nullptr, 1.f, 0, 0, 0, qkvF, nullptr, nullptr, nullptr, nullptr, 0, zpg);
        attn_kernel<<<dim3(B_ * NH_), blk, 0, stream>>>(qkvF, ctxH, ctxL);
        gemm_s<64><<<dim3(H_ / 64, M_ / 128), blk, 0, stream>>>(
            ctxH, ctxL, H_, 0, 0, 0, woH, woL, H_, H_,
            nullptr, trunkF, 1.f, 0, 0, 0, trunkF, nullptr, nullptr, nullptr, nullptr, 0, zpg);
        ln_kernel<<<dim3(M_ / 4), blk, 0, stream>>>(trunkF, ln2_g, ln2_b, xn2H, xn2L);
        for (int half = 0; half < 2; half++) {
            int ro = half * MH_;
            gemm_s<128><<<dim3(FS_ / 128, MH_ / 128), blk, 0, stream>>>(
                xn2H, xn2L, H_, 1, ro, ro, W1H, W1L, FS_, 3 * H_,
                c1_b, nullptr, 1.f, 1, 0, 2, nullptr, y1H, y1L, nullptr, nullptr, 0, zpg);
            gemm_s<64><<<dim3(H_ / 64, MH_ / 128, 2), blk, 0, stream>>>(
                y1H, y1L, FS_, 1, 0, ro, W2H, W2L, H_, 3 * FS_ / 2,
                nullptr, nullptr, 1.f, 0, 0, 3, partF, nullptr, nullptr, nullptr, nullptr,
                (long)MH_ * H_, zpg);
            conv2_reduce<<<dim3((unsigned)((long)MH_ * H_ / 4 / 256)), blk, 0, stream>>>(
                partF, (long)MH_ * H_, c2_b, trunkF, prevF, uwF, ro);
        }
    }

    // --- output head ---
    pooled_kernel<<<dim3(B_ * H_ / 256), blk, 0, stream>>>(prevF, pooledH, pooledL);
    esplit_kernel<<<dim3(64000), blk, 0, stream>>>(emb, embH, embL, (long)V_ * H_);
    gemm_s<64><<<dim3(V_ / 64, B_ / 128), blk, 0, stream>>>(
        pooledH, pooledL, H_, 0, 0, 0, embH, embL, V_, H_,
        out_b, nullptr, 1.f, 0, 0, 0, outp, nullptr, nullptr, nullptr, nullptr, 0, zpg);
    softmax_kernel<<<dim3(B_), blk, 0, stream>>>(outp, outp + (long)B_ * V_);
    tails_kernel<<<dim3((M_ + 255) / 256), blk, 0, stream>>>(remF, nuF, outp + 2L * B_ * V_);
}

// Round 6
// 8220.376 us; speedup vs baseline: 1.6678x; 1.3331x over previous
//
#include <hip/hip_runtime.h>
#include <hip/hip_bf16.h>
#include <math.h>

// ---------------------------------------------------------------------------
// BabiUTransformer (Universal Transformer + ACT) on gfx950.  All float I/O fp32.
// GEMMs: split-precision bf16 MFMA (hh+lh+hl, err ~2^-18 rel). Activations are
// pre-split into hi/lo bf16 planes by their PRODUCER kernels.
// Round-4 design (3rd submit; r4/r5 benches were container-acquisition
// failures, not kernel verdicts -- audited twice for wedge hazards, none):
// TAP-FUSED conv kernel (gemm_conv): the 3 conv taps read the same
// A rows shifted +-1, so stage a 130-row A slab ONCE per 32-wide c-chunk and
// run all 3 taps against it -> 3x MFMA per barrier (72/wave/K-step), /3
// A-staging, K-loop 48->16 steps (conv1) / 96->32 (conv2 half).  Edge zeroing
// by per-lane fragment masks (l==0 kills tap0, l==70 kills tap2) - identical
// numerics to the old zpg pointer redirect.  conv2 additionally gets a
// bijective XCD group-swizzle (1-D grid, chunked decode) so each XCD owns
// contiguous (by,z,halfN) groups: A-panel + B-half fit the 4MB XCD L2 ->
// A refetch 8x -> 2x (r3 counters: FETCH 1.06 GB/dispatch from bn-pinned XCDs).
// Non-conv GEMMs (proj/qkv/wo/head) keep the r3 gemm_s (TN 64/128).
// LDS: [group16][kchunk8][row16] subtiles; fragment ds_read_b128s conflict-free
// (verified 0 since r1); lane permutation carried on the per-lane GLOBAL source
// address of global_load_lds (width 16).
// Attention: LDS stride padded 64->65. ACT any()-gate via device flag.
// ---------------------------------------------------------------------------

typedef unsigned short ushort_t;
using short8  = __attribute__((ext_vector_type(8))) short;
using floatx4 = __attribute__((ext_vector_type(4))) float;

#define B_   256
#define L_   71
#define H_   512
#define M_   (B_*L_)      // 18176 rows (142 x 128); half = 9088 (71 x 128)
#define MH_  9088
#define FS_  2048
#define V_   32000
#define NH_  8
#define DK_  64

__device__ inline ushort_t f2bf_rne(float f) {
    unsigned u = __float_as_uint(f);
    return (ushort_t)((u + 0x7FFFu + ((u >> 16) & 1u)) >> 16);
}

// async global->LDS, 16B per lane. LDS dest must be wave-uniform base
// (hardware writes base + lane*16); global src is per-lane.
__device__ __forceinline__ void gload16(const void* g, void* l)
{
    __builtin_amdgcn_global_load_lds(
        (__attribute__((address_space(1))) unsigned int*)(g),
        (__attribute__((address_space(3))) unsigned int*)(l),
        16, 0, 0);
}

// ---------------------------------------------------------------------------
// Tap-fused conv GEMM: C[m,n] = sum_d sum_c A[m-1+d, c] * B[n, d*C + c]
// A planes [rows, C=lda]; B planes [N, 3*lda]. TM=128, TN=64, 4 waves (each
// 32 rows x 64 cols, 2x4 frags x 3 taps x 3 split = 72 MFMA / K-step).
// A slab: 144 rows staged (130 used), 9 groups; B: 3 taps x 4 groups.
// MODE 0 (conv1): bias+relu -> bf16 hi/lo out [grow*N].
// MODE 1 (conv2): f32 partial -> Cpart + z*partStride (split over c).
// Grid: MODE 0: (32, 71) natural.  MODE 1: 1136 1-D, swizzled decode.
// ---------------------------------------------------------------------------
template<int MODE>
__global__ __launch_bounds__(256) void gemm_conv(
    const ushort_t* __restrict__ AH, const ushort_t* __restrict__ AL,
    int lda, int rowA, int rowG,
    const ushort_t* __restrict__ Bh, const ushort_t* __restrict__ Bl,
    int N, const float* __restrict__ bias,
    ushort_t* __restrict__ CoutH, ushort_t* __restrict__ CoutL,
    float* __restrict__ Cpart, long partStride, int cLen)
{
    __shared__ __attribute__((aligned(16))) short Ahs[4608], Als[4608];
    __shared__ __attribute__((aligned(16))) short Bhs[6144], Bls[6144];

    const int tid  = threadIdx.x;
    const int w    = tid >> 6, lane = tid & 63;

    int bn, by, z;
    if (MODE == 1) {
        // bijective chunked XCD swizzle: xcd = id%8; contiguous logical ids
        // per XCD; logical = (by,z,halfN)-group * 4 + member.
        const int id = blockIdx.x;               // 0..1135
        const int l  = (id & 7) * 142 + (id >> 3);
        const int gp = l >> 2;                   // 0..283
        by = gp % 71;
        const int zz = gp / 71;                  // 0..3
        z  = zz >> 1;
        bn = (zz & 1) * 4 + (l & 3);             // 0..7
    } else {
        bn = blockIdx.x; by = blockIdx.y; z = 0;
    }
    const int cBeg = z * cLen;
    const int bm = by << 7;

    // ---- staging setup ----
    const int srow = lane & 15, skc = lane >> 4;
    // A units: u in {w, w+4} (+ u=8 for wave 0); slab row u*16+srow = global
    // row rowA + bm - 1 + u*16 + srow; col = c0 + skc*8.
    const long aOff0 = (long)(rowA + bm - 1 + (w    ) * 16 + srow) * lda + skc * 8;
    const long aOff1 = (long)(rowA + bm - 1 + (w + 4) * 16 + srow) * lda + skc * 8;
    const long aOff2 = (long)(rowA + bm - 1 + 128 + srow) * lda + skc * 8;  // u=8
    // B units: u in {w, w+4, w+8} of 12 (tap d = u>>2, group gb = u&3)
    const long ldb = 3L * lda;
    const long bOff0 = (long)(bn * 64 + ((w    ) & 3) * 16 + srow) * ldb + ((w    ) >> 2) * lda + skc * 8;
    const long bOff1 = (long)(bn * 64 + ((w + 4) & 3) * 16 + srow) * ldb + ((w + 4) >> 2) * lda + skc * 8;
    const long bOff2 = (long)(bn * 64 + ((w + 8) & 3) * 16 + srow) * ldb + ((w + 8) >> 2) * lda + skc * 8;

    // ---- fragment read offsets ----
    const int quad = lane >> 4, mr = lane & 15;
    const int boffL = quad * 128 + mr * 8;
    int aoffs[2][3];
    bool am0[2], am2[2];
    #pragma unroll
    for (int i = 0; i < 2; i++) {
        #pragma unroll
        for (int d = 0; d < 3; d++) {
            const int s = w * 32 + i * 16 + mr + d;   // slab row
            aoffs[i][d] = (s >> 4) * 512 + quad * 128 + (s & 15) * 8;
        }
        const int lm = (bm + w * 32 + i * 16 + mr + rowG) % 71;
        am0[i] = (lm == 0);
        am2[i] = (lm == 70);
    }

    floatx4 acc[2][4] = {};

    const int cEnd = cBeg + cLen;
    for (int c0 = cBeg; c0 < cEnd; c0 += 32) {
        __syncthreads();   // previous step's ds_reads done before overwrite
        gload16(AH + aOff0 + c0, Ahs + (w    ) * 512);
        gload16(AH + aOff1 + c0, Ahs + (w + 4) * 512);
        gload16(AL + aOff0 + c0, Als + (w    ) * 512);
        gload16(AL + aOff1 + c0, Als + (w + 4) * 512);
        if (w == 0) {
            gload16(AH + aOff2 + c0, Ahs + 8 * 512);
            gload16(AL + aOff2 + c0, Als + 8 * 512);
        }
        gload16(Bh + bOff0 + c0, Bhs + (w    ) * 512);
        gload16(Bh + bOff1 + c0, Bhs + (w + 4) * 512);
        gload16(Bh + bOff2 + c0, Bhs + (w + 8) * 512);
        gload16(Bl + bOff0 + c0, Bls + (w    ) * 512);
        gload16(Bl + bOff1 + c0, Bls + (w + 4) * 512);
        gload16(Bl + bOff2 + c0, Bls + (w + 8) * 512);
        __syncthreads();   // loads landed (compiler drains vmcnt here)

        #pragma unroll
        for (int d = 0; d < 3; d++) {
            short8 bhf[4], blf[4];
            #pragma unroll
            for (int j = 0; j < 4; j++) {
                bhf[j] = *(const short8*)(Bhs + (d * 4 + j) * 512 + boffL);
                blf[j] = *(const short8*)(Bls + (d * 4 + j) * 512 + boffL);
            }
            #pragma unroll
            for (int i = 0; i < 2; i++) {
                short8 a_h = *(const short8*)(Ahs + aoffs[i][d]);
                short8 a_l = *(const short8*)(Als + aoffs[i][d]);
                if (d == 0) { if (am0[i]) { a_h = (short8)0; a_l = (short8)0; } }
                if (d == 2) { if (am2[i]) { a_h = (short8)0; a_l = (short8)0; } }
                #pragma unroll
                for (int j = 0; j < 4; j++) {
                    acc[i][j] = __builtin_amdgcn_mfma_f32_16x16x32_bf16(a_h, bhf[j], acc[i][j], 0, 0, 0);
                    acc[i][j] = __builtin_amdgcn_mfma_f32_16x16x32_bf16(a_l, bhf[j], acc[i][j], 0, 0, 0);
                    acc[i][j] = __builtin_amdgcn_mfma_f32_16x16x32_bf16(a_h, blf[j], acc[i][j], 0, 0, 0);
                }
            }
        }
    }

    // C/D layout: col = lane&15, row = quad*4 + r
    #pragma unroll
    for (int j = 0; j < 4; j++) {
        const int gcol = bn * 64 + j * 16 + mr;
        const float bv = (MODE == 0) ? bias[gcol] : 0.f;
        #pragma unroll
        for (int i = 0; i < 2; i++) {
            #pragma unroll
            for (int r = 0; r < 4; r++) {
                const int grow = bm + w * 32 + i * 16 + quad * 4 + r;
                float v = acc[i][j][r];
                if (MODE == 0) {
                    v = fmaxf(v + bv, 0.f);
                    const long cidx = (long)grow * N + gcol;
                    ushort_t h = f2bf_rne(v);
                    float hf = __uint_as_float(((unsigned)h) << 16);
                    CoutH[cidx] = h;
                    CoutL[cidx] = f2bf_rne(v - hf);
                } else {
                    Cpart[(long)z * partStride + (long)grow * N + gcol] = v;
                }
            }
        }
    }
}

// ---------------------------------------------------------------------------
// Split GEMM (non-conv): C[M,N] = alpha*(A @ B) (+bias)(+residual)
// A pre-split hi/lo bf16 planes [rows, lda]. B hi/lo planes [N,K] row-major.
// outMode: 0 = f32 out; 2 = bf16 hi/lo out.
// Tile TM=128 x TN (64 or 128), BK=32, 4 waves, 256 threads.
// ---------------------------------------------------------------------------
template<int TN>
__global__ __launch_bounds__(256) void gemm_s(
    const ushort_t* __restrict__ AH, const ushort_t* __restrict__ AL,
    int lda, int rowA,
    const ushort_t* __restrict__ Bh, const ushort_t* __restrict__ Bl,
    int N, int K,
    const float* __restrict__ bias, const float* residual,
    float alpha, int rowC, int outMode,
    float* Cout, ushort_t* CoutH, ushort_t* CoutL)
{
    constexpr int AF = (TN == 128) ? 4 : 2;   // a-frags per wave
    __shared__ __attribute__((aligned(16))) short Ahs[4096], Als[4096];
    __shared__ __attribute__((aligned(16))) short Bhs[TN * 32], Bls[TN * 32];

    const int tid  = threadIdx.x;
    const int w    = tid >> 6, lane = tid & 63;
    const int bm = blockIdx.y << 7, bn = blockIdx.x * TN;

    const int srow = lane & 15;
    const int skc  = lane >> 4;
    const int ra0  = w * 16 + srow;
    const int ra1  = ra0 + 64;
    const ushort_t* pAh0 = AH + (long)(bm + ra0 + rowA) * lda + skc * 8;
    const ushort_t* pAl0 = AL + (long)(bm + ra0 + rowA) * lda + skc * 8;
    const ushort_t* pAh1 = AH + (long)(bm + ra1 + rowA) * lda + skc * 8;
    const ushort_t* pAl1 = AL + (long)(bm + ra1 + rowA) * lda + skc * 8;
    const ushort_t* pBh0 = Bh + (long)(bn + ra0) * K + skc * 8;
    const ushort_t* pBl0 = Bl + (long)(bn + ra0) * K + skc * 8;
    const ushort_t* pBh1 = (TN == 128) ? (Bh + (long)(bn + ra1) * K + skc * 8) : nullptr;
    const ushort_t* pBl1 = (TN == 128) ? (Bl + (long)(bn + ra1) * K + skc * 8) : nullptr;

    const int quad = lane >> 4, mr = lane & 15;
    const int wrM   = (TN == 128) ? ((w >> 1) << 6) : (w << 5);
    const int wcN   = (TN == 128) ? ((w & 1) << 6) : 0;
    const int agrp0 = (TN == 128) ? ((w >> 1) << 2) : (w << 1);
    const int bgrp0 = (TN == 128) ? ((w & 1) << 2) : 0;
    const int foff  = quad * 128 + mr * 8;

    floatx4 acc[AF][4] = {};

    for (int k0 = 0; k0 < K; k0 += 32) {
        __syncthreads();
        gload16(pAh0 + k0, Ahs + w * 512);
        gload16(pAh1 + k0, Ahs + (w + 4) * 512);
        gload16(pAl0 + k0, Als + w * 512);
        gload16(pAl1 + k0, Als + (w + 4) * 512);
        if constexpr (TN == 128) {
            gload16(pBh0 + k0, Bhs + w * 512);
            gload16(pBh1 + k0, Bhs + (w + 4) * 512);
            gload16(pBl0 + k0, Bls + w * 512);
            gload16(pBl1 + k0, Bls + (w + 4) * 512);
        } else {
            gload16(pBh0 + k0, Bhs + w * 512);
            gload16(pBl0 + k0, Bls + w * 512);
        }
        __syncthreads();

        short8 ah[AF], al[AF], bh[4], bl[4];
        #pragma unroll
        for (int i = 0; i < AF; i++) {
            ah[i] = *(const short8*)(Ahs + (agrp0 + i) * 512 + foff);
            al[i] = *(const short8*)(Als + (agrp0 + i) * 512 + foff);
        }
        #pragma unroll
        for (int j = 0; j < 4; j++) {
            bh[j] = *(const short8*)(Bhs + (bgrp0 + j) * 512 + foff);
            bl[j] = *(const short8*)(Bls + (bgrp0 + j) * 512 + foff);
        }
        #pragma unroll
        for (int i = 0; i < AF; i++)
        #pragma unroll
        for (int j = 0; j < 4; j++) {
            acc[i][j] = __builtin_amdgcn_mfma_f32_16x16x32_bf16(ah[i], bh[j], acc[i][j], 0, 0, 0);
            acc[i][j] = __builtin_amdgcn_mfma_f32_16x16x32_bf16(al[i], bh[j], acc[i][j], 0, 0, 0);
            acc[i][j] = __builtin_amdgcn_mfma_f32_16x16x32_bf16(ah[i], bl[j], acc[i][j], 0, 0, 0);
        }
    }

    #pragma unroll
    for (int j = 0; j < 4; j++) {
        const int gcol = bn + wcN + j * 16 + mr;
        const float bv = bias ? bias[gcol] : 0.f;
        #pragma unroll
        for (int i = 0; i < AF; i++) {
            #pragma unroll
            for (int r = 0; r < 4; r++) {
                const int grow = bm + wrM + i * 16 + quad * 4 + r;
                const long crow = (long)grow + rowC;
                float v = acc[i][j][r] * alpha + bv;
                if (residual) v += residual[crow * N + gcol];
                const long cidx = crow * (long)N + gcol;
                if (outMode == 2) {
                    ushort_t h = f2bf_rne(v);
                    float hf = __uint_as_float(((unsigned)h) << 16);
                    CoutH[cidx] = h;
                    CoutL[cidx] = f2bf_rne(v - hf);
                } else {
                    Cout[cidx] = v;
                }
            }
        }
    }
}

// split-K=2 reduce for conv2: v = p0+p1+bias+trunk; trunk=v; prev update.
__global__ __launch_bounds__(256) void conv2_reduce(
    const float* __restrict__ part, long partStride,
    const float* __restrict__ bias, float* __restrict__ trunk,
    float* __restrict__ prev, const float* __restrict__ uw, int rowC)
{
    const long n4 = (long)MH_ * H_ / 4;
    long i4 = (long)blockIdx.x * 256 + threadIdx.x;
    if (i4 >= n4) return;
    const long row  = i4 >> 7;            // 0..9087 (128 float4 per row)
    const float4 p0 = ((const float4*)part)[i4];
    const float4 p1 = ((const float4*)(part + partStride))[i4];
    const float4 b4 = ((const float4*)bias)[i4 & 127];
    const long  ti  = (long)rowC * 128 + i4;
    float4 tv = ((const float4*)trunk)[ti];
    float4 v;
    v.x = p0.x + p1.x + b4.x + tv.x;
    v.y = p0.y + p1.y + b4.y + tv.y;
    v.z = p0.z + p1.z + b4.z + tv.z;
    v.w = p0.w + p1.w + b4.w + tv.w;
    ((float4*)trunk)[ti] = v;
    const float u = uw[rowC + row];
    float4 pv = ((const float4*)prev)[ti];
    pv.x = v.x * u + pv.x * (1.f - u);
    pv.y = v.y * u + pv.y * (1.f - u);
    pv.z = v.z * u + pv.z * (1.f - u);
    pv.w = v.w * u + pv.w * (1.f - u);
    ((float4*)prev)[ti] = pv;
}

// Timing-signal tables, float32 math (matches numpy float32 exp/sin chain).
__global__ __launch_bounds__(256) void sig_prep(float* __restrict__ T, float* __restrict__ P)
{
    int i = blockIdx.x * 256 + threadIdx.x;
    const int NT = 71 * 512;
    if (i >= NT + 6 * 512) return;
    int pos, c, idx;
    float* dst;
    if (i < NT) { pos = i >> 9; c = i & 511; dst = T; idx = i; }
    else        { int j = i - NT; pos = j >> 9; c = j & 511; dst = P; idx = j; }
    const float loginc = 0.036119766f;
    int jj = c & 255;
    float inv = expf(-(float)jj * loginc);
    float arg = (float)pos * inv;
    dst[idx] = (c < 256) ? sinf(arg) : cosf(arg);
}

// active-gate: flag |= any(hp<0.9 && nu<6)   (ballot, 1 atomic/wave)
__global__ __launch_bounds__(256) void gate_kernel(
    const float* __restrict__ hp, const float* __restrict__ nu, int* __restrict__ flag)
{
    int i = blockIdx.x * 256 + threadIdx.x;
    bool act = (i < M_) && (hp[i] < 0.9f) && (nu[i] < 6.0f);
    unsigned long long b = __ballot(act);
    if ((threadIdx.x & 63) == 0 && b) atomicOr(flag, 1);
}

// s = state + T[l] + P[t] (in-place); pr = sigmoid(s.p_w+p_b); gated ACT.
__global__ __launch_bounds__(256) void s_pr_kernel(
    float* trunk, const float* __restrict__ Ttab, const float* __restrict__ Ptab,
    const float* __restrict__ p_w, const float* __restrict__ p_b,
    float* __restrict__ hp, float* __restrict__ rem, float* __restrict__ nu,
    float* __restrict__ uw, const int* __restrict__ flag, int t)
{
    const int row  = blockIdx.x * 4 + (threadIdx.x >> 6);
    const int lane = threadIdx.x & 63;
    const int l    = row % 71;
    float dot = 0.f;
    #pragma unroll
    for (int j = 0; j < 8; j++) {
        int c  = lane + 64 * j;
        float sv = trunk[(long)row * H_ + c] + Ttab[l * H_ + c] + Ptab[t * H_ + c];
        trunk[(long)row * H_ + c] = sv;
        dot += sv * p_w[c];
    }
    #pragma unroll
    for (int o = 32; o; o >>= 1) dot += __shfl_xor(dot, o);
    if (lane == 0) {
        if (flag[0]) {
            float pr = 1.f / (1.f + expf(-(dot + p_b[0])));
            float hp0 = hp[row], rem0 = rem[row], nu0 = nu[row];
            float still = (hp0 < 1.0f) ? 1.f : 0.f;
            float tot   = hp0 + pr * still;
            float nh    = ((tot > 0.9f) ? 1.f : 0.f) * still;
            float st2   = ((tot <= 0.9f) ? 1.f : 0.f) * still;
            float hp2   = hp0 + pr * st2;
            float rem2  = rem0 + nh * (1.f - hp2);
            hp2 += nh * rem2;
            hp[row] = hp2; rem[row] = rem2; nu[row] = nu0 + st2 + nh;
            uw[row] = pr * st2 + nh * rem2;
        } else {
            uw[row] = 0.f;
        }
    }
}

// LayerNorm fp32 -> bf16 hi/lo planes.
__global__ __launch_bounds__(256) void ln_kernel(
    const float* __restrict__ X, const float* __restrict__ g,
    const float* __restrict__ bb, ushort_t* __restrict__ outH,
    ushort_t* __restrict__ outL)
{
    const int row  = blockIdx.x * 4 + (threadIdx.x >> 6);
    const int lane = threadIdx.x & 63;
    const float* xr = X + (long)row * H_;
    float v[8];
    float s = 0.f;
    #pragma unroll
    for (int j = 0; j < 8; j++) { v[j] = xr[lane + 64 * j]; s += v[j]; }
    #pragma unroll
    for (int o = 32; o; o >>= 1) s += __shfl_xor(s, o);
    float mean = s * (1.f / 512.f);
    float q = 0.f;
    #pragma unroll
    for (int j = 0; j < 8; j++) { float d = v[j] - mean; q += d * d; }
    #pragma unroll
    for (int o = 32; o; o >>= 1) q += __shfl_xor(q, o);
    float sd  = sqrtf(q * (1.f / 511.f));
    float inv = 1.f / (sd + 1e-6f);
    #pragma unroll
    for (int j = 0; j < 8; j++) {
        int c = lane + 64 * j;
        float val = g[c] * (v[j] - mean) * inv + bb[c];
        ushort_t h = f2bf_rne(val);
        float hf = __uint_as_float(((unsigned)h) << 16);
        long idx = (long)row * H_ + c;
        outH[idx] = h;
        outL[idx] = f2bf_rne(val - hf);
    }
}

// Attention, fp32, LDS stride 65 (conflict-free). One block per (b,h).
// q pre-scaled by 1/8 (folded into wq split). qkv fused [M,1536]:
// q at +0, k at +512, v at +1024. ctx written as bf16 hi/lo planes [M,512].
__global__ __launch_bounds__(256) void attn_kernel(
    const float* __restrict__ qkv, ushort_t* __restrict__ ctxH,
    ushort_t* __restrict__ ctxL)
{
    __shared__ float qs[L_ * 65];
    __shared__ float ks[L_ * 65];   // reused for V
    __shared__ float Ss[L_ * L_];
    const int tid = threadIdx.x;
    const int b = blockIdx.x >> 3, h = blockIdx.x & 7;
    const long qbase = (long)b * L_ * 1536 + h * DK_;
    for (int idx = tid; idx < L_ * DK_; idx += 256) {
        int i = idx >> 6, d = idx & 63;
        qs[i * 65 + d] = qkv[qbase + (long)i * 1536 + d];
        ks[i * 65 + d] = qkv[qbase + 512 + (long)i * 1536 + d];
    }
    __syncthreads();
    for (int idx = tid; idx < L_ * L_; idx += 256) {
        int i = idx / 71, j = idx % 71;
        const float* qr = qs + i * 65;
        const float* kr = ks + j * 65;
        float s0 = 0.f, s1 = 0.f, s2 = 0.f, s3 = 0.f;
        #pragma unroll
        for (int d = 0; d < 64; d += 4) {
            s0 += qr[d]     * kr[d];
            s1 += qr[d + 1] * kr[d + 1];
            s2 += qr[d + 2] * kr[d + 2];
            s3 += qr[d + 3] * kr[d + 3];
        }
        Ss[i * 71 + j] = (s0 + s1) + (s2 + s3);
    }
    __syncthreads();
    if (tid < L_) {
        float mx = -1e30f;
        for (int j = 0; j < L_; j++) mx = fmaxf(mx, Ss[tid * 71 + j]);
        float sm = 0.f;
        for (int j = 0; j < L_; j++) { float e = expf(Ss[tid * 71 + j] - mx); Ss[tid * 71 + j] = e; sm += e; }
        float inv = 1.f / sm;
        for (int j = 0; j < L_; j++) Ss[tid * 71 + j] *= inv;
    }
    for (int idx = tid; idx < L_ * DK_; idx += 256) {
        int i = idx >> 6, d = idx & 63;
        ks[i * 65 + d] = qkv[qbase + 1024 + (long)i * 1536 + d];
    }
    __syncthreads();
    const long obase = (long)b * L_ * H_ + h * DK_;
    for (int idx = tid; idx < L_ * DK_; idx += 256) {
        int i = idx >> 6, d = idx & 63;
        const float* sr = Ss + i * 71;
        float s0 = 0.f, s1 = 0.f;
        int j = 0;
        for (; j + 1 < L_; j += 2) {
            s0 += sr[j]     * ks[j * 65 + d];
            s1 += sr[j + 1] * ks[(j + 1) * 65 + d];
        }
        float s = s0 + s1 + sr[70] * ks[70 * 65 + d];
        ushort_t hh = f2bf_rne(s);
        float hf = __uint_as_float(((unsigned)hh) << 16);
        long o = obase + (long)i * H_ + d;
        ctxH[o] = hh;
        ctxL[o] = f2bf_rne(s - hf);
    }
}

// Embedding -> bf16 hi/lo planes
__global__ __launch_bounds__(256) void embed_kernel(
    const int* __restrict__ story, const int* __restrict__ query,
    const float* __restrict__ emb, const float* __restrict__ mask,
    ushort_t* __restrict__ xH, ushort_t* __restrict__ xL)
{
    __shared__ int idx[11];
    const int row = blockIdx.x;
    const int b = row / 71, m = row % 71;
    const int tid = threadIdx.x;
    if (tid < 11)
        idx[tid] = (m < 70) ? story[((long)b * 70 + m) * 11 + tid]
                            : query[(long)b * 11 + tid];
    __syncthreads();
    for (int c = tid; c < H_; c += 256) {
        float acc = 0.f;
        #pragma unroll
        for (int s = 0; s < 11; s++)
            acc += emb[(long)idx[s] * H_ + c] * mask[s * H_ + c];
        ushort_t h = f2bf_rne(acc);
        float hf = __uint_as_float(((unsigned)h) << 16);
        long o = (long)row * H_ + c;
        xH[o] = h;
        xL[o] = f2bf_rne(acc - hf);
    }
}

// transpose + scale + split fp32 [R,C] -> bf16 hi/lo planes rows rowOff.., ld=R
__global__ __launch_bounds__(256) void wsplitT_kernel(
    const float* __restrict__ in, ushort_t* __restrict__ hi, ushort_t* __restrict__ lo,
    int R, int C, int rowOff, float scale)
{
    long i = (long)blockIdx.x * 256 + threadIdx.x;
    if (i < (long)R * C) {
        int r = (int)(i / C), c = (int)(i % C);
        float f = in[i] * scale;
        ushort_t h = f2bf_rne(f);
        float hf = __uint_as_float(((unsigned)h) << 16);
        hi[(long)(c + rowOff) * R + r] = h;
        lo[(long)(c + rowOff) * R + r] = f2bf_rne(f - hf);
    }
}

// conv weight gather+split: plane[n*(3C) + d*C + c] = w[(n*C + c)*3 + d]
__global__ __launch_bounds__(256) void convw_split_kernel(
    const float* __restrict__ w, ushort_t* __restrict__ hi, ushort_t* __restrict__ lo,
    int N, int C)
{
    long i = (long)blockIdx.x * 256 + threadIdx.x;
    if (i < (long)N * C * 3) {
        int n = (int)(i / (3 * C));
        int r = (int)(i % (3 * C));
        int d = r / C, c = r % C;
        float f = w[((long)n * C + c) * 3 + d];
        ushort_t h = f2bf_rne(f);
        float hf = __uint_as_float(((unsigned)h) << 16);
        hi[i] = h;
        lo[i] = f2bf_rne(f - hf);
    }
}

// plain split: emb [V,E] -> hi/lo planes same layout
__global__ __launch_bounds__(256) void esplit_kernel(
    const float* __restrict__ in, ushort_t* __restrict__ hi, ushort_t* __restrict__ lo,
    long n)
{
    long i = (long)blockIdx.x * 256 + threadIdx.x;
    if (i < n) {
        float f = in[i];
        ushort_t h = f2bf_rne(f);
        float hf = __uint_as_float(((unsigned)h) << 16);
        hi[i] = h;
        lo[i] = f2bf_rne(f - hf);
    }
}

__global__ __launch_bounds__(256) void zero_f32(float* __restrict__ p, long n)
{
    long i = (long)blockIdx.x * 256 + threadIdx.x;
    if (i < n) p[i] = 0.f;
}

// pooled[b,c] = (sum_l prev[b,l,c]) / 71 -> bf16 hi/lo planes
__global__ __launch_bounds__(256) void pooled_kernel(
    const float* __restrict__ prev, ushort_t* __restrict__ pH, ushort_t* __restrict__ pL)
{
    int i = blockIdx.x * 256 + threadIdx.x;   // [0, 256*512)
    int b = i >> 9, c = i & 511;
    float s = 0.f;
    for (int l = 0; l < L_; l++) s += prev[((long)b * L_ + l) * H_ + c];
    float p = s / 71.0f;
    ushort_t h = f2bf_rne(p);
    float hf = __uint_as_float(((unsigned)h) << 16);
    pH[i] = h;
    pL[i] = f2bf_rne(p - hf);
}

__global__ __launch_bounds__(256) void softmax_kernel(
    const float* __restrict__ ah, float* __restrict__ out)
{
    __shared__ float red[256];
    const int b = blockIdx.x, tid = threadIdx.x;
    const float* a = ah + (long)b * V_;
    float mx = -1e30f;
    for (int i = tid; i < V_; i += 256) mx = fmaxf(mx, a[i]);
    red[tid] = mx; __syncthreads();
    for (int o = 128; o; o >>= 1) { if (tid < o) red[tid] = fmaxf(red[tid], red[tid + o]); __syncthreads(); }
    mx = red[0]; __syncthreads();
    float s = 0.f;
    for (int i = tid; i < V_; i += 256) s += expf(a[i] - mx);
    red[tid] = s; __syncthreads();
    for (int o = 128; o; o >>= 1) { if (tid < o) red[tid] += red[tid + o]; __syncthreads(); }
    float inv = 1.f / red[0];
    float* o_ = out + (long)b * V_;
    for (int i = tid; i < V_; i += 256) o_[i] = expf(a[i] - mx) * inv;
}

__global__ __launch_bounds__(256) void tails_kernel(
    const float* __restrict__ rem, const float* __restrict__ nu, float* __restrict__ out)
{
    int i = blockIdx.x * 256 + threadIdx.x;
    if (i < M_) {
        out[i] = rem[i];
        out[M_ + i] = nu[i];
    }
}

// ---------------------------------------------------------------------------
extern "C" void kernel_launch(void* const* d_in, const int* in_sizes, int n_in,
                              void* d_out, int out_size, void* d_ws, size_t ws_size,
                              hipStream_t stream)
{
    const int*   story  = (const int*)d_in[0];
    const int*   query  = (const int*)d_in[1];
    const float* emb    = (const float*)d_in[2];
    const float* mask_p = (const float*)d_in[3];
    const float* proj_w = (const float*)d_in[4];
    const float* ln1_g  = (const float*)d_in[5];
    const float* ln1_b  = (const float*)d_in[6];
    const float* wq     = (const float*)d_in[7];
    const float* wk     = (const float*)d_in[8];
    const float* wv     = (const float*)d_in[9];
    const float* wo     = (const float*)d_in[10];
    const float* c1_w   = (const float*)d_in[11];
    const float* c1_b   = (const float*)d_in[12];
    const float* c2_w   = (const float*)d_in[13];
    const float* c2_b   = (const float*)d_in[14];
    const float* ln2_g  = (const float*)d_in[15];
    const float* ln2_b  = (const float*)d_in[16];
    const float* p_w    = (const float*)d_in[17];
    const float* p_b    = (const float*)d_in[18];
    const float* out_b  = (const float*)d_in[19];
    float* outp = (float*)d_out;

    char* wsb = (char*)d_ws;
    size_t off = 0;
    auto alloc = [&](size_t bytes) -> void* {
        void* p = wsb + off;
        off = (off + bytes + 255) & ~(size_t)255;
        return p;
    };
    const long ROWE = (long)M_ * H_;             // 9,306,112 elements

    float* trunkF = (float*)alloc(ROWE * 4);
    float* prevF  = (float*)alloc(ROWE * 4);
    char*  poolC  = (char*)alloc(4L * ROWE * 4); // 148.9 MB multi-purpose pool
    float* hpF    = (float*)alloc((long)M_ * 4 * 4 + 64);
    float* remF   = hpF + M_;
    float* nuF    = hpF + 2 * M_;
    float* uwF    = hpF + 3 * M_;
    int*   flags  = (int*)(hpF + 4 * M_);
    ushort_t* projH = (ushort_t*)alloc((long)H_ * H_ * 2);
    ushort_t* projL = (ushort_t*)alloc((long)H_ * H_ * 2);
    ushort_t* wqkvH = (ushort_t*)alloc((long)3 * H_ * H_ * 2);
    ushort_t* wqkvL = (ushort_t*)alloc((long)3 * H_ * H_ * 2);
    ushort_t* woH   = (ushort_t*)alloc((long)H_ * H_ * 2);
    ushort_t* woL   = (ushort_t*)alloc((long)H_ * H_ * 2);
    ushort_t* W1H   = (ushort_t*)alloc((long)FS_ * 3 * H_ * 2);
    ushort_t* W1L   = (ushort_t*)alloc((long)FS_ * 3 * H_ * 2);
    ushort_t* W2H   = (ushort_t*)alloc((long)H_ * 3 * FS_ * 2);
    ushort_t* W2L   = (ushort_t*)alloc((long)H_ * 3 * FS_ * 2);
    ushort_t* pooledH = (ushort_t*)alloc((long)B_ * H_ * 2);
    ushort_t* pooledL = (ushort_t*)alloc((long)B_ * H_ * 2);
    float* Ttab     = (float*)alloc((long)L_ * H_ * 4);
    float* Ptab     = (float*)alloc(6L * H_ * 4);

    // pool aliases (phases disjoint in time):
    ushort_t* xnH = (ushort_t*)poolC;
    ushort_t* xnL = xnH + ROWE;
    float* qkvF = (float*)(poolC + ROWE * 4);            // 3*ROWE floats
    ushort_t* ctxH = xnH;
    ushort_t* ctxL = xnL;
    ushort_t* xn2H = (ushort_t*)poolC;
    ushort_t* xn2L = xn2H + ROWE;
    ushort_t* y1H  = (ushort_t*)(poolC + ROWE * 4);
    ushort_t* y1L  = y1H + (long)MH_ * FS_;
    float* partF   = (float*)(poolC + ROWE * 4 + (long)MH_ * FS_ * 4);  // 2 x MH_*H_ f32
    ushort_t* xembH = (ushort_t*)poolC;
    ushort_t* xembL = xembH + ROWE;
    ushort_t* embH = (ushort_t*)poolC;
    ushort_t* embL = embH + (long)V_ * H_;

    dim3 blk(256);

    // --- init (ws re-poisoned every call) ---
    zero_f32<<<dim3((unsigned)((ROWE + 255) / 256)), blk, 0, stream>>>(prevF, ROWE);
    zero_f32<<<dim3((3 * M_ + 255) / 256), blk, 0, stream>>>(hpF, 3 * M_);
    zero_f32<<<dim3(1), blk, 0, stream>>>((float*)flags, 16);
    sig_prep<<<dim3(154), blk, 0, stream>>>(Ttab, Ptab);

    // --- weight prep: transpose + hi/lo split (q-scale 1/8 folded, bit-exact) ---
    wsplitT_kernel<<<dim3(1024), blk, 0, stream>>>(proj_w, projH, projL, H_, H_, 0, 1.f);
    wsplitT_kernel<<<dim3(1024), blk, 0, stream>>>(wq, wqkvH, wqkvL, H_, H_, 0, 0.125f);
    wsplitT_kernel<<<dim3(1024), blk, 0, stream>>>(wk, wqkvH, wqkvL, H_, H_, 512, 1.f);
    wsplitT_kernel<<<dim3(1024), blk, 0, stream>>>(wv, wqkvH, wqkvL, H_, H_, 1024, 1.f);
    wsplitT_kernel<<<dim3(1024), blk, 0, stream>>>(wo, woH, woL, H_, H_, 0, 1.f);
    convw_split_kernel<<<dim3(12288), blk, 0, stream>>>(c1_w, W1H, W1L, FS_, H_);
    convw_split_kernel<<<dim3(12288), blk, 0, stream>>>(c2_w, W2H, W2L, H_, FS_);

    // --- embedding + input projection ---
    embed_kernel<<<dim3(M_), blk, 0, stream>>>(story, query, emb, mask_p, xembH, xembL);
    gemm_s<64><<<dim3(H_ / 64, M_ / 128), blk, 0, stream>>>(
        xembH, xembL, H_, 0, projH, projL, H_, H_,
        nullptr, nullptr, 1.f, 0, 0, trunkF, nullptr, nullptr);

    // --- ACT loop: 6 steps with faithful any()-gate ---
    for (int t = 0; t < 6; t++) {
        gate_kernel<<<dim3(M_ / 256), blk, 0, stream>>>(hpF, nuF, flags + t);
        s_pr_kernel<<<dim3(M_ / 4), blk, 0, stream>>>(trunkF, Ttab, Ptab, p_w, p_b,
                                                      hpF, remF, nuF, uwF, flags + t, t);
        ln_kernel<<<dim3(M_ / 4), blk, 0, stream>>>(trunkF, ln1_g, ln1_b, xnH, xnL);
        gemm_s<128><<<dim3(1536 / 128, M_ / 128), blk, 0, stream>>>(
            xnH, xnL, H_, 0, wqkvH, wqkvL, 1536, H_,
            nullptr, nullptr, 1.f, 0, 0, qkvF, nullptr, nullptr);
        attn_kernel<<<dim3(B_ * NH_), blk, 0, stream>>>(qkvF, ctxH, ctxL);
        gemm_s<64><<<dim3(H_ / 64, M_ / 128), blk, 0, stream>>>(
            ctxH, ctxL, H_, 0, woH, woL, H_, H_,
            nullptr, trunkF, 1.f, 0, 0, trunkF, nullptr, nullptr);
        ln_kernel<<<dim3(M_ / 4), blk, 0, stream>>>(trunkF, ln2_g, ln2_b, xn2H, xn2L);
        for (int half = 0; half < 2; half++) {
            int ro = half * MH_;
            gemm_conv<0><<<dim3(32, 71), blk, 0, stream>>>(
                xn2H, xn2L, H_, ro, ro, W1H, W1L, FS_,
                c1_b, y1H, y1L, nullptr, 0, 512);
            gemm_conv<1><<<dim3(1136), blk, 0, stream>>>(
                y1H, y1L, FS_, 0, ro, W2H, W2L, H_,
                nullptr, nullptr, nullptr, partF, (long)MH_ * H_, 1024);
            conv2_reduce<<<dim3((unsigned)((long)MH_ * H_ / 4 / 256)), blk, 0, stream>>>(
                partF, (long)MH_ * H_, c2_b, trunkF, prevF, uwF, ro);
        }
    }

    // --- output head ---
    pooled_kernel<<<dim3(B_ * H_ / 256), blk, 0, stream>>>(prevF, pooledH, pooledL);
    esplit_kernel<<<dim3(64000), blk, 0, stream>>>(emb, embH, embL, (long)V_ * H_);
    gemm_s<64><<<dim3(V_ / 64, B_ / 128), blk, 0, stream>>>(
        pooledH, pooledL, H_, 0, embH, embL, V_, H_,
        out_b, nullptr, 1.f, 0, 0, outp, nullptr, nullptr);
    softmax_kernel<<<dim3(B_), blk, 0, stream>>>(outp, outp + (long)B_ * V_);
    tails_kernel<<<dim3((M_ + 255) / 256), blk, 0, stream>>>(remF, nuF, outp + 2L * B_ * V_);
}

// Round 7
// 7820.808 us; speedup vs baseline: 1.7530x; 1.0511x over previous
//
#include <hip/hip_runtime.h>
#include <hip/hip_bf16.h>
#include <math.h>

// ---------------------------------------------------------------------------
// BabiUTransformer (Universal Transformer + ACT) on gfx950.  All float I/O fp32.
// GEMMs: split-precision bf16 MFMA (hh+lh+hl, err ~2^-18 rel). Activations are
// pre-split into hi/lo bf16 planes by their PRODUCER kernels.
// r6 verdict: tap-fused conv = WIN (10.96 -> 8.22 ms).  r7 (this round):
// attn_kernel rewrite -- r6 counters showed attn is LDS-read-ISSUE bound
// (MfmaUtil 0, VALUBusy 40%, HBM 5%; 128 scalar ds_read_b32 per score).
// New attn: float4 (b128) LDS reads with 16B-aligned strides (68/72),
// register-blocked QK^T (4 j-outputs/item: 1 q + 4 k b128 per 4-k-chunk,
// k-reads wave-broadcast), wave-parallel softmax (4 lanes/row, shfl reduce),
// deferred normalization (unnormalized exp + rsum[i] folded into PV epilogue).
// K/V padded to 72 rows, row 71 zeroed; j=71 masked to -inf pre-max -> no NaN.
// Conv kernels unchanged from r6 (tap-fused, XCD-swizzled conv2).
// ---------------------------------------------------------------------------

typedef unsigned short ushort_t;
using short8   = __attribute__((ext_vector_type(8))) short;
using floatx4  = __attribute__((ext_vector_type(4))) float;
using ushort4v = __attribute__((ext_vector_type(4))) unsigned short;

#define B_   256
#define L_   71
#define H_   512
#define M_   (B_*L_)      // 18176 rows (142 x 128); half = 9088 (71 x 128)
#define MH_  9088
#define FS_  2048
#define V_   32000
#define NH_  8
#define DK_  64

#define ATS  68           // attn q/k/v LDS row stride (floats), 272B (16B-aligned)
#define SST  72           // attn S LDS row stride (floats), 288B (16B-aligned)

__device__ inline ushort_t f2bf_rne(float f) {
    unsigned u = __float_as_uint(f);
    return (ushort_t)((u + 0x7FFFu + ((u >> 16) & 1u)) >> 16);
}

// async global->LDS, 16B per lane. LDS dest must be wave-uniform base
// (hardware writes base + lane*16); global src is per-lane.
__device__ __forceinline__ void gload16(const void* g, void* l)
{
    __builtin_amdgcn_global_load_lds(
        (__attribute__((address_space(1))) unsigned int*)(g),
        (__attribute__((address_space(3))) unsigned int*)(l),
        16, 0, 0);
}

// ---------------------------------------------------------------------------
// Tap-fused conv GEMM (unchanged from r6): C[m,n] = sum_d sum_c A[m-1+d,c]*B[n,d*C+c]
// ---------------------------------------------------------------------------
template<int MODE>
__global__ __launch_bounds__(256) void gemm_conv(
    const ushort_t* __restrict__ AH, const ushort_t* __restrict__ AL,
    int lda, int rowA, int rowG,
    const ushort_t* __restrict__ Bh, const ushort_t* __restrict__ Bl,
    int N, const float* __restrict__ bias,
    ushort_t* __restrict__ CoutH, ushort_t* __restrict__ CoutL,
    float* __restrict__ Cpart, long partStride, int cLen)
{
    __shared__ __attribute__((aligned(16))) short Ahs[4608], Als[4608];
    __shared__ __attribute__((aligned(16))) short Bhs[6144], Bls[6144];

    const int tid  = threadIdx.x;
    const int w    = tid >> 6, lane = tid & 63;

    int bn, by, z;
    if (MODE == 1) {
        const int id = blockIdx.x;               // 0..1135
        const int l  = (id & 7) * 142 + (id >> 3);
        const int gp = l >> 2;                   // 0..283
        by = gp % 71;
        const int zz = gp / 71;                  // 0..3
        z  = zz >> 1;
        bn = (zz & 1) * 4 + (l & 3);             // 0..7
    } else {
        bn = blockIdx.x; by = blockIdx.y; z = 0;
    }
    const int cBeg = z * cLen;
    const int bm = by << 7;

    const int srow = lane & 15, skc = lane >> 4;
    const long aOff0 = (long)(rowA + bm - 1 + (w    ) * 16 + srow) * lda + skc * 8;
    const long aOff1 = (long)(rowA + bm - 1 + (w + 4) * 16 + srow) * lda + skc * 8;
    const long aOff2 = (long)(rowA + bm - 1 + 128 + srow) * lda + skc * 8;  // u=8
    const long ldb = 3L * lda;
    const long bOff0 = (long)(bn * 64 + ((w    ) & 3) * 16 + srow) * ldb + ((w    ) >> 2) * lda + skc * 8;
    const long bOff1 = (long)(bn * 64 + ((w + 4) & 3) * 16 + srow) * ldb + ((w + 4) >> 2) * lda + skc * 8;
    const long bOff2 = (long)(bn * 64 + ((w + 8) & 3) * 16 + srow) * ldb + ((w + 8) >> 2) * lda + skc * 8;

    const int quad = lane >> 4, mr = lane & 15;
    const int boffL = quad * 128 + mr * 8;
    int aoffs[2][3];
    bool am0[2], am2[2];
    #pragma unroll
    for (int i = 0; i < 2; i++) {
        #pragma unroll
        for (int d = 0; d < 3; d++) {
            const int s = w * 32 + i * 16 + mr + d;   // slab row
            aoffs[i][d] = (s >> 4) * 512 + quad * 128 + (s & 15) * 8;
        }
        const int lm = (bm + w * 32 + i * 16 + mr + rowG) % 71;
        am0[i] = (lm == 0);
        am2[i] = (lm == 70);
    }

    floatx4 acc[2][4] = {};

    const int cEnd = cBeg + cLen;
    for (int c0 = cBeg; c0 < cEnd; c0 += 32) {
        __syncthreads();
        gload16(AH + aOff0 + c0, Ahs + (w    ) * 512);
        gload16(AH + aOff1 + c0, Ahs + (w + 4) * 512);
        gload16(AL + aOff0 + c0, Als + (w    ) * 512);
        gload16(AL + aOff1 + c0, Als + (w + 4) * 512);
        if (w == 0) {
            gload16(AH + aOff2 + c0, Ahs + 8 * 512);
            gload16(AL + aOff2 + c0, Als + 8 * 512);
        }
        gload16(Bh + bOff0 + c0, Bhs + (w    ) * 512);
        gload16(Bh + bOff1 + c0, Bhs + (w + 4) * 512);
        gload16(Bh + bOff2 + c0, Bhs + (w + 8) * 512);
        gload16(Bl + bOff0 + c0, Bls + (w    ) * 512);
        gload16(Bl + bOff1 + c0, Bls + (w + 4) * 512);
        gload16(Bl + bOff2 + c0, Bls + (w + 8) * 512);
        __syncthreads();

        #pragma unroll
        for (int d = 0; d < 3; d++) {
            short8 bhf[4], blf[4];
            #pragma unroll
            for (int j = 0; j < 4; j++) {
                bhf[j] = *(const short8*)(Bhs + (d * 4 + j) * 512 + boffL);
                blf[j] = *(const short8*)(Bls + (d * 4 + j) * 512 + boffL);
            }
            #pragma unroll
            for (int i = 0; i < 2; i++) {
                short8 a_h = *(const short8*)(Ahs + aoffs[i][d]);
                short8 a_l = *(const short8*)(Als + aoffs[i][d]);
                if (d == 0) { if (am0[i]) { a_h = (short8)0; a_l = (short8)0; } }
                if (d == 2) { if (am2[i]) { a_h = (short8)0; a_l = (short8)0; } }
                #pragma unroll
                for (int j = 0; j < 4; j++) {
                    acc[i][j] = __builtin_amdgcn_mfma_f32_16x16x32_bf16(a_h, bhf[j], acc[i][j], 0, 0, 0);
                    acc[i][j] = __builtin_amdgcn_mfma_f32_16x16x32_bf16(a_l, bhf[j], acc[i][j], 0, 0, 0);
                    acc[i][j] = __builtin_amdgcn_mfma_f32_16x16x32_bf16(a_h, blf[j], acc[i][j], 0, 0, 0);
                }
            }
        }
    }

    #pragma unroll
    for (int j = 0; j < 4; j++) {
        const int gcol = bn * 64 + j * 16 + mr;
        const float bv = (MODE == 0) ? bias[gcol] : 0.f;
        #pragma unroll
        for (int i = 0; i < 2; i++) {
            #pragma unroll
            for (int r = 0; r < 4; r++) {
                const int grow = bm + w * 32 + i * 16 + quad * 4 + r;
                float v = acc[i][j][r];
                if (MODE == 0) {
                    v = fmaxf(v + bv, 0.f);
                    const long cidx = (long)grow * N + gcol;
                    ushort_t h = f2bf_rne(v);
                    float hf = __uint_as_float(((unsigned)h) << 16);
                    CoutH[cidx] = h;
                    CoutL[cidx] = f2bf_rne(v - hf);
                } else {
                    Cpart[(long)z * partStride + (long)grow * N + gcol] = v;
                }
            }
        }
    }
}

// ---------------------------------------------------------------------------
// Split GEMM (non-conv, unchanged from r6)
// ---------------------------------------------------------------------------
template<int TN>
__global__ __launch_bounds__(256) void gemm_s(
    const ushort_t* __restrict__ AH, const ushort_t* __restrict__ AL,
    int lda, int rowA,
    const ushort_t* __restrict__ Bh, const ushort_t* __restrict__ Bl,
    int N, int K,
    const float* __restrict__ bias, const float* residual,
    float alpha, int rowC, int outMode,
    float* Cout, ushort_t* CoutH, ushort_t* CoutL)
{
    constexpr int AF = (TN == 128) ? 4 : 2;   // a-frags per wave
    __shared__ __attribute__((aligned(16))) short Ahs[4096], Als[4096];
    __shared__ __attribute__((aligned(16))) short Bhs[TN * 32], Bls[TN * 32];

    const int tid  = threadIdx.x;
    const int w    = tid >> 6, lane = tid & 63;
    const int bm = blockIdx.y << 7, bn = blockIdx.x * TN;

    const int srow = lane & 15;
    const int skc  = lane >> 4;
    const int ra0  = w * 16 + srow;
    const int ra1  = ra0 + 64;
    const ushort_t* pAh0 = AH + (long)(bm + ra0 + rowA) * lda + skc * 8;
    const ushort_t* pAl0 = AL + (long)(bm + ra0 + rowA) * lda + skc * 8;
    const ushort_t* pAh1 = AH + (long)(bm + ra1 + rowA) * lda + skc * 8;
    const ushort_t* pAl1 = AL + (long)(bm + ra1 + rowA) * lda + skc * 8;
    const ushort_t* pBh0 = Bh + (long)(bn + ra0) * K + skc * 8;
    const ushort_t* pBl0 = Bl + (long)(bn + ra0) * K + skc * 8;
    const ushort_t* pBh1 = (TN == 128) ? (Bh + (long)(bn + ra1) * K + skc * 8) : nullptr;
    const ushort_t* pBl1 = (TN == 128) ? (Bl + (long)(bn + ra1) * K + skc * 8) : nullptr;

    const int quad = lane >> 4, mr = lane & 15;
    const int wrM   = (TN == 128) ? ((w >> 1) << 6) : (w << 5);
    const int wcN   = (TN == 128) ? ((w & 1) << 6) : 0;
    const int agrp0 = (TN == 128) ? ((w >> 1) << 2) : (w << 1);
    const int bgrp0 = (TN == 128) ? ((w & 1) << 2) : 0;
    const int foff  = quad * 128 + mr * 8;

    floatx4 acc[AF][4] = {};

    for (int k0 = 0; k0 < K; k0 += 32) {
        __syncthreads();
        gload16(pAh0 + k0, Ahs + w * 512);
        gload16(pAh1 + k0, Ahs + (w + 4) * 512);
        gload16(pAl0 + k0, Als + w * 512);
        gload16(pAl1 + k0, Als + (w + 4) * 512);
        if constexpr (TN == 128) {
            gload16(pBh0 + k0, Bhs + w * 512);
            gload16(pBh1 + k0, Bhs + (w + 4) * 512);
            gload16(pBl0 + k0, Bls + w * 512);
            gload16(pBl1 + k0, Bls + (w + 4) * 512);
        } else {
            gload16(pBh0 + k0, Bhs + w * 512);
            gload16(pBl0 + k0, Bls + w * 512);
        }
        __syncthreads();

        short8 ah[AF], al[AF], bh[4], bl[4];
        #pragma unroll
        for (int i = 0; i < AF; i++) {
            ah[i] = *(const short8*)(Ahs + (agrp0 + i) * 512 + foff);
            al[i] = *(const short8*)(Als + (agrp0 + i) * 512 + foff);
        }
        #pragma unroll
        for (int j = 0; j < 4; j++) {
            bh[j] = *(const short8*)(Bhs + (bgrp0 + j) * 512 + foff);
            bl[j] = *(const short8*)(Bls + (bgrp0 + j) * 512 + foff);
        }
        #pragma unroll
        for (int i = 0; i < AF; i++)
        #pragma unroll
        for (int j = 0; j < 4; j++) {
            acc[i][j] = __builtin_amdgcn_mfma_f32_16x16x32_bf16(ah[i], bh[j], acc[i][j], 0, 0, 0);
            acc[i][j] = __builtin_amdgcn_mfma_f32_16x16x32_bf16(al[i], bh[j], acc[i][j], 0, 0, 0);
            acc[i][j] = __builtin_amdgcn_mfma_f32_16x16x32_bf16(ah[i], bl[j], acc[i][j], 0, 0, 0);
        }
    }

    #pragma unroll
    for (int j = 0; j < 4; j++) {
        const int gcol = bn + wcN + j * 16 + mr;
        const float bv = bias ? bias[gcol] : 0.f;
        #pragma unroll
        for (int i = 0; i < AF; i++) {
            #pragma unroll
            for (int r = 0; r < 4; r++) {
                const int grow = bm + wrM + i * 16 + quad * 4 + r;
                const long crow = (long)grow + rowC;
                float v = acc[i][j][r] * alpha + bv;
                if (residual) v += residual[crow * N + gcol];
                const long cidx = crow * (long)N + gcol;
                if (outMode == 2) {
                    ushort_t h = f2bf_rne(v);
                    float hf = __uint_as_float(((unsigned)h) << 16);
                    CoutH[cidx] = h;
                    CoutL[cidx] = f2bf_rne(v - hf);
                } else {
                    Cout[cidx] = v;
                }
            }
        }
    }
}

// split-K=2 reduce for conv2: v = p0+p1+bias+trunk; trunk=v; prev update.
__global__ __launch_bounds__(256) void conv2_reduce(
    const float* __restrict__ part, long partStride,
    const float* __restrict__ bias, float* __restrict__ trunk,
    float* __restrict__ prev, const float* __restrict__ uw, int rowC)
{
    const long n4 = (long)MH_ * H_ / 4;
    long i4 = (long)blockIdx.x * 256 + threadIdx.x;
    if (i4 >= n4) return;
    const long row  = i4 >> 7;            // 0..9087 (128 float4 per row)
    const float4 p0 = ((const float4*)part)[i4];
    const float4 p1 = ((const float4*)(part + partStride))[i4];
    const float4 b4 = ((const float4*)bias)[i4 & 127];
    const long  ti  = (long)rowC * 128 + i4;
    float4 tv = ((const float4*)trunk)[ti];
    float4 v;
    v.x = p0.x + p1.x + b4.x + tv.x;
    v.y = p0.y + p1.y + b4.y + tv.y;
    v.z = p0.z + p1.z + b4.z + tv.z;
    v.w = p0.w + p1.w + b4.w + tv.w;
    ((float4*)trunk)[ti] = v;
    const float u = uw[rowC + row];
    float4 pv = ((const float4*)prev)[ti];
    pv.x = v.x * u + pv.x * (1.f - u);
    pv.y = v.y * u + pv.y * (1.f - u);
    pv.z = v.z * u + pv.z * (1.f - u);
    pv.w = v.w * u + pv.w * (1.f - u);
    ((float4*)prev)[ti] = pv;
}

// Timing-signal tables, float32 math (matches numpy float32 exp/sin chain).
__global__ __launch_bounds__(256) void sig_prep(float* __restrict__ T, float* __restrict__ P)
{
    int i = blockIdx.x * 256 + threadIdx.x;
    const int NT = 71 * 512;
    if (i >= NT + 6 * 512) return;
    int pos, c, idx;
    float* dst;
    if (i < NT) { pos = i >> 9; c = i & 511; dst = T; idx = i; }
    else        { int j = i - NT; pos = j >> 9; c = j & 511; dst = P; idx = j; }
    const float loginc = 0.036119766f;
    int jj = c & 255;
    float inv = expf(-(float)jj * loginc);
    float arg = (float)pos * inv;
    dst[idx] = (c < 256) ? sinf(arg) : cosf(arg);
}

// active-gate: flag |= any(hp<0.9 && nu<6)   (ballot, 1 atomic/wave)
__global__ __launch_bounds__(256) void gate_kernel(
    const float* __restrict__ hp, const float* __restrict__ nu, int* __restrict__ flag)
{
    int i = blockIdx.x * 256 + threadIdx.x;
    bool act = (i < M_) && (hp[i] < 0.9f) && (nu[i] < 6.0f);
    unsigned long long b = __ballot(act);
    if ((threadIdx.x & 63) == 0 && b) atomicOr(flag, 1);
}

// s = state + T[l] + P[t] (in-place); pr = sigmoid(s.p_w+p_b); gated ACT.
__global__ __launch_bounds__(256) void s_pr_kernel(
    float* trunk, const float* __restrict__ Ttab, const float* __restrict__ Ptab,
    const float* __restrict__ p_w, const float* __restrict__ p_b,
    float* __restrict__ hp, float* __restrict__ rem, float* __restrict__ nu,
    float* __restrict__ uw, const int* __restrict__ flag, int t)
{
    const int row  = blockIdx.x * 4 + (threadIdx.x >> 6);
    const int lane = threadIdx.x & 63;
    const int l    = row % 71;
    float dot = 0.f;
    #pragma unroll
    for (int j = 0; j < 8; j++) {
        int c  = lane + 64 * j;
        float sv = trunk[(long)row * H_ + c] + Ttab[l * H_ + c] + Ptab[t * H_ + c];
        trunk[(long)row * H_ + c] = sv;
        dot += sv * p_w[c];
    }
    #pragma unroll
    for (int o = 32; o; o >>= 1) dot += __shfl_xor(dot, o);
    if (lane == 0) {
        if (flag[0]) {
            float pr = 1.f / (1.f + expf(-(dot + p_b[0])));
            float hp0 = hp[row], rem0 = rem[row], nu0 = nu[row];
            float still = (hp0 < 1.0f) ? 1.f : 0.f;
            float tot   = hp0 + pr * still;
            float nh    = ((tot > 0.9f) ? 1.f : 0.f) * still;
            float st2   = ((tot <= 0.9f) ? 1.f : 0.f) * still;
            float hp2   = hp0 + pr * st2;
            float rem2  = rem0 + nh * (1.f - hp2);
            hp2 += nh * rem2;
            hp[row] = hp2; rem[row] = rem2; nu[row] = nu0 + st2 + nh;
            uw[row] = pr * st2 + nh * rem2;
        } else {
            uw[row] = 0.f;
        }
    }
}

// LayerNorm fp32 -> bf16 hi/lo planes.
__global__ __launch_bounds__(256) void ln_kernel(
    const float* __restrict__ X, const float* __restrict__ g,
    const float* __restrict__ bb, ushort_t* __restrict__ outH,
    ushort_t* __restrict__ outL)
{
    const int row  = blockIdx.x * 4 + (threadIdx.x >> 6);
    const int lane = threadIdx.x & 63;
    const float* xr = X + (long)row * H_;
    float v[8];
    float s = 0.f;
    #pragma unroll
    for (int j = 0; j < 8; j++) { v[j] = xr[lane + 64 * j]; s += v[j]; }
    #pragma unroll
    for (int o = 32; o; o >>= 1) s += __shfl_xor(s, o);
    float mean = s * (1.f / 512.f);
    float q = 0.f;
    #pragma unroll
    for (int j = 0; j < 8; j++) { float d = v[j] - mean; q += d * d; }
    #pragma unroll
    for (int o = 32; o; o >>= 1) q += __shfl_xor(q, o);
    float sd  = sqrtf(q * (1.f / 511.f));
    float inv = 1.f / (sd + 1e-6f);
    #pragma unroll
    for (int j = 0; j < 8; j++) {
        int c = lane + 64 * j;
        float val = g[c] * (v[j] - mean) * inv + bb[c];
        ushort_t h = f2bf_rne(val);
        float hf = __uint_as_float(((unsigned)h) << 16);
        long idx = (long)row * H_ + c;
        outH[idx] = h;
        outL[idx] = f2bf_rne(val - hf);
    }
}

// ---------------------------------------------------------------------------
// Attention v2, fp32, LDS-b128 vectorized.  One block per (b,h), 256 threads.
// q pre-scaled by 1/8 (folded into wq split). qkv fused [M,1536]:
// q at +0, k at +512, v at +1024. ctx written as bf16 hi/lo planes [M,512].
// QK^T: item (jq,i) -> S[i][4jq..+3]; per 4-k chunk: 1 q b128 + 4 k b128
// (k wave-broadcast).  Softmax: 4 lanes/row, shfl reduce, deferred norm
// (exp unnormalized in Ss, rsum[i]=1/sum applied in PV epilogue).
// K/V rows padded to 72; row 71 zeroed; j=71 masked to -inf before max.
// ---------------------------------------------------------------------------
__global__ __launch_bounds__(256) void attn_kernel(
    const float* __restrict__ qkv, ushort_t* __restrict__ ctxH,
    ushort_t* __restrict__ ctxL)
{
    __shared__ __attribute__((aligned(16))) float qs[L_ * ATS];        // 19312 B
    __shared__ __attribute__((aligned(16))) float ks[(L_ + 1) * ATS];  // 19584 B (V reuses)
    __shared__ __attribute__((aligned(16))) float Ss[L_ * SST];        // 20448 B
    __shared__ float rsum[L_ + 1];
    const int tid = threadIdx.x;
    const int b = blockIdx.x >> 3, h = blockIdx.x & 7;
    const long qbase = (long)b * L_ * 1536 + h * DK_;

    // ---- stage Q,K (float4); zero K row 71 ----
    for (int idx = tid; idx < L_ * 16; idx += 256) {
        const int i = idx >> 4, s4 = idx & 15;
        const float4 qv = *(const float4*)(qkv + qbase + (long)i * 1536 + 4 * s4);
        const float4 kv = *(const float4*)(qkv + qbase + 512 + (long)i * 1536 + 4 * s4);
        *(float4*)(qs + i * ATS + 4 * s4) = qv;
        *(float4*)(ks + i * ATS + 4 * s4) = kv;
    }
    if (tid < 16) {
        float4 zz = {0.f, 0.f, 0.f, 0.f};
        *(float4*)(ks + 71 * ATS + 4 * tid) = zz;
    }
    __syncthreads();

    // ---- QK^T: 18 j-quads x 71 rows = 1278 items ----
    for (int item = tid; item < 18 * L_; item += 256) {
        const int jq = item / 71, i = item - jq * 71;
        const float* qr = qs + i * ATS;
        const float* k0 = ks + (4 * jq) * ATS;
        float s0 = 0.f, s1 = 0.f, s2 = 0.f, s3 = 0.f;
        #pragma unroll
        for (int s4 = 0; s4 < 16; s4++) {
            const float4 qv = *(const float4*)(qr + 4 * s4);
            const float4 k0v = *(const float4*)(k0 + 4 * s4);
            const float4 k1v = *(const float4*)(k0 + ATS + 4 * s4);
            const float4 k2v = *(const float4*)(k0 + 2 * ATS + 4 * s4);
            const float4 k3v = *(const float4*)(k0 + 3 * ATS + 4 * s4);
            s0 += qv.x * k0v.x + qv.y * k0v.y + qv.z * k0v.z + qv.w * k0v.w;
            s1 += qv.x * k1v.x + qv.y * k1v.y + qv.z * k1v.z + qv.w * k1v.w;
            s2 += qv.x * k2v.x + qv.y * k2v.y + qv.z * k2v.z + qv.w * k2v.w;
            s3 += qv.x * k3v.x + qv.y * k3v.y + qv.z * k3v.z + qv.w * k3v.w;
        }
        float4 sv; sv.x = s0; sv.y = s1; sv.z = s2; sv.w = s3;
        *(float4*)(Ss + i * SST + 4 * jq) = sv;
    }
    __syncthreads();

    // ---- re-stage V into ks (rows 0..70; row 71 stays zero) ----
    for (int idx = tid; idx < L_ * 16; idx += 256) {
        const int i = idx >> 4, s4 = idx & 15;
        *(float4*)(ks + i * ATS + 4 * s4) =
            *(const float4*)(qkv + qbase + 1024 + (long)i * 1536 + 4 * s4);
    }

    // ---- softmax: 4 lanes per row; rows {g, g+64}; deferred normalization ----
    {
        const int g = tid >> 2, r = tid & 3;
        #pragma unroll
        for (int half = 0; half < 2; half++) {
            const int row = g + half * 64;
            if (row < L_) {
                float4 vals[5];
                float mx = -1e30f;
                #pragma unroll
                for (int t = 0; t < 5; t++) {
                    const int q = r + 4 * t;
                    if (q < 18) {
                        float4 v = *(const float4*)(Ss + row * SST + 4 * q);
                        if (q == 17) v.w = -1e30f;   // j = 71 pad
                        vals[t] = v;
                        mx = fmaxf(mx, fmaxf(fmaxf(v.x, v.y), fmaxf(v.z, v.w)));
                    }
                }
                mx = fmaxf(mx, __shfl_xor(mx, 1));
                mx = fmaxf(mx, __shfl_xor(mx, 2));
                float sm = 0.f;
                #pragma unroll
                for (int t = 0; t < 5; t++) {
                    const int q = r + 4 * t;
                    if (q < 18) {
                        float4 v = vals[t];
                        v.x = expf(v.x - mx); v.y = expf(v.y - mx);
                        v.z = expf(v.z - mx); v.w = expf(v.w - mx);
                        sm += v.x + v.y + v.z + v.w;
                        *(float4*)(Ss + row * SST + 4 * q) = v;
                    }
                }
                sm += __shfl_xor(sm, 1);
                sm += __shfl_xor(sm, 2);
                if (r == 0) rsum[row] = 1.f / sm;
            }
        }
    }
    __syncthreads();

    // ---- PV: item (i,dq) -> ctx[i][4dq..+3]; lanes share i (v-reads spread) ----
    const long obase = (long)b * L_ * H_ + h * DK_;
    for (int item = tid; item < L_ * 16; item += 256) {
        const int i = item >> 4, dq = item & 15;
        const float* sr = Ss + i * SST;
        float ax = 0.f, ay = 0.f, az = 0.f, aw = 0.f;
        #pragma unroll
        for (int jq = 0; jq < 18; jq++) {
            const float4 sv = *(const float4*)(sr + 4 * jq);
            const float* v0 = ks + (4 * jq) * ATS + 4 * dq;
            const float4 va = *(const float4*)(v0);
            const float4 vb = *(const float4*)(v0 + ATS);
            const float4 vc = *(const float4*)(v0 + 2 * ATS);
            const float4 vd = *(const float4*)(v0 + 3 * ATS);
            ax += sv.x * va.x + sv.y * vb.x + sv.z * vc.x + sv.w * vd.x;
            ay += sv.x * va.y + sv.y * vb.y + sv.z * vc.y + sv.w * vd.y;
            az += sv.x * va.z + sv.y * vb.z + sv.z * vc.z + sv.w * vd.z;
            aw += sv.x * va.w + sv.y * vb.w + sv.z * vc.w + sv.w * vd.w;
        }
        const float rs = rsum[i];
        float o[4] = {ax * rs, ay * rs, az * rs, aw * rs};
        ushort4v hv, lv;
        #pragma unroll
        for (int c = 0; c < 4; c++) {
            ushort_t hh = f2bf_rne(o[c]);
            float hf = __uint_as_float(((unsigned)hh) << 16);
            hv[c] = hh;
            lv[c] = f2bf_rne(o[c] - hf);
        }
        const long oo = obase + (long)i * H_ + 4 * dq;
        *(ushort4v*)(ctxH + oo) = hv;
        *(ushort4v*)(ctxL + oo) = lv;
    }
}

// Embedding -> bf16 hi/lo planes
__global__ __launch_bounds__(256) void embed_kernel(
    const int* __restrict__ story, const int* __restrict__ query,
    const float* __restrict__ emb, const float* __restrict__ mask,
    ushort_t* __restrict__ xH, ushort_t* __restrict__ xL)
{
    __shared__ int idx[11];
    const int row = blockIdx.x;
    const int b = row / 71, m = row % 71;
    const int tid = threadIdx.x;
    if (tid < 11)
        idx[tid] = (m < 70) ? story[((long)b * 70 + m) * 11 + tid]
                            : query[(long)b * 11 + tid];
    __syncthreads();
    for (int c = tid; c < H_; c += 256) {
        float acc = 0.f;
        #pragma unroll
        for (int s = 0; s < 11; s++)
            acc += emb[(long)idx[s] * H_ + c] * mask[s * H_ + c];
        ushort_t h = f2bf_rne(acc);
        float hf = __uint_as_float(((unsigned)h) << 16);
        long o = (long)row * H_ + c;
        xH[o] = h;
        xL[o] = f2bf_rne(acc - hf);
    }
}

// transpose + scale + split fp32 [R,C] -> bf16 hi/lo planes rows rowOff.., ld=R
__global__ __launch_bounds__(256) void wsplitT_kernel(
    const float* __restrict__ in, ushort_t* __restrict__ hi, ushort_t* __restrict__ lo,
    int R, int C, int rowOff, float scale)
{
    long i = (long)blockIdx.x * 256 + threadIdx.x;
    if (i < (long)R * C) {
        int r = (int)(i / C), c = (int)(i % C);
        float f = in[i] * scale;
        ushort_t h = f2bf_rne(f);
        float hf = __uint_as_float(((unsigned)h) << 16);
        hi[(long)(c + rowOff) * R + r] = h;
        lo[(long)(c + rowOff) * R + r] = f2bf_rne(f - hf);
    }
}

// conv weight gather+split: plane[n*(3C) + d*C + c] = w[(n*C + c)*3 + d]
__global__ __launch_bounds__(256) void convw_split_kernel(
    const float* __restrict__ w, ushort_t* __restrict__ hi, ushort_t* __restrict__ lo,
    int N, int C)
{
    long i = (long)blockIdx.x * 256 + threadIdx.x;
    if (i < (long)N * C * 3) {
        int n = (int)(i / (3 * C));
        int r = (int)(i % (3 * C));
        int d = r / C, c = r % C;
        float f = w[((long)n * C + c) * 3 + d];
        ushort_t h = f2bf_rne(f);
        float hf = __uint_as_float(((unsigned)h) << 16);
        hi[i] = h;
        lo[i] = f2bf_rne(f - hf);
    }
}

// plain split: emb [V,E] -> hi/lo planes same layout
__global__ __launch_bounds__(256) void esplit_kernel(
    const float* __restrict__ in, ushort_t* __restrict__ hi, ushort_t* __restrict__ lo,
    long n)
{
    long i = (long)blockIdx.x * 256 + threadIdx.x;
    if (i < n) {
        float f = in[i];
        ushort_t h = f2bf_rne(f);
        float hf = __uint_as_float(((unsigned)h) << 16);
        hi[i] = h;
        lo[i] = f2bf_rne(f - hf);
    }
}

__global__ __launch_bounds__(256) void zero_f32(float* __restrict__ p, long n)
{
    long i = (long)blockIdx.x * 256 + threadIdx.x;
    if (i < n) p[i] = 0.f;
}

// pooled[b,c] = (sum_l prev[b,l,c]) / 71 -> bf16 hi/lo planes
__global__ __launch_bounds__(256) void pooled_kernel(
    const float* __restrict__ prev, ushort_t* __restrict__ pH, ushort_t* __restrict__ pL)
{
    int i = blockIdx.x * 256 + threadIdx.x;   // [0, 256*512)
    int b = i >> 9, c = i & 511;
    float s = 0.f;
    for (int l = 0; l < L_; l++) s += prev[((long)b * L_ + l) * H_ + c];
    float p = s / 71.0f;
    ushort_t h = f2bf_rne(p);
    float hf = __uint_as_float(((unsigned)h) << 16);
    pH[i] = h;
    pL[i] = f2bf_rne(p - hf);
}

__global__ __launch_bounds__(256) void softmax_kernel(
    const float* __restrict__ ah, float* __restrict__ out)
{
    __shared__ float red[256];
    const int b = blockIdx.x, tid = threadIdx.x;
    const float* a = ah + (long)b * V_;
    float mx = -1e30f;
    for (int i = tid; i < V_; i += 256) mx = fmaxf(mx, a[i]);
    red[tid] = mx; __syncthreads();
    for (int o = 128; o; o >>= 1) { if (tid < o) red[tid] = fmaxf(red[tid], red[tid + o]); __syncthreads(); }
    mx = red[0]; __syncthreads();
    float s = 0.f;
    for (int i = tid; i < V_; i += 256) s += expf(a[i] - mx);
    red[tid] = s; __syncthreads();
    for (int o = 128; o; o >>= 1) { if (tid < o) red[tid] += red[tid + o]; __syncthreads(); }
    float inv = 1.f / red[0];
    float* o_ = out + (long)b * V_;
    for (int i = tid; i < V_; i += 256) o_[i] = expf(a[i] - mx) * inv;
}

__global__ __launch_bounds__(256) void tails_kernel(
    const float* __restrict__ rem, const float* __restrict__ nu, float* __restrict__ out)
{
    int i = blockIdx.x * 256 + threadIdx.x;
    if (i < M_) {
        out[i] = rem[i];
        out[M_ + i] = nu[i];
    }
}

// ---------------------------------------------------------------------------
extern "C" void kernel_launch(void* const* d_in, const int* in_sizes, int n_in,
                              void* d_out, int out_size, void* d_ws, size_t ws_size,
                              hipStream_t stream)
{
    const int*   story  = (const int*)d_in[0];
    const int*   query  = (const int*)d_in[1];
    const float* emb    = (const float*)d_in[2];
    const float* mask_p = (const float*)d_in[3];
    const float* proj_w = (const float*)d_in[4];
    const float* ln1_g  = (const float*)d_in[5];
    const float* ln1_b  = (const float*)d_in[6];
    const float* wq     = (const float*)d_in[7];
    const float* wk     = (const float*)d_in[8];
    const float* wv     = (const float*)d_in[9];
    const float* wo     = (const float*)d_in[10];
    const float* c1_w   = (const float*)d_in[11];
    const float* c1_b   = (const float*)d_in[12];
    const float* c2_w   = (const float*)d_in[13];
    const float* c2_b   = (const float*)d_in[14];
    const float* ln2_g  = (const float*)d_in[15];
    const float* ln2_b  = (const float*)d_in[16];
    const float* p_w    = (const float*)d_in[17];
    const float* p_b    = (const float*)d_in[18];
    const float* out_b  = (const float*)d_in[19];
    float* outp = (float*)d_out;

    char* wsb = (char*)d_ws;
    size_t off = 0;
    auto alloc = [&](size_t bytes) -> void* {
        void* p = wsb + off;
        off = (off + bytes + 255) & ~(size_t)255;
        return p;
    };
    const long ROWE = (long)M_ * H_;             // 9,306,112 elements

    float* trunkF = (float*)alloc(ROWE * 4);
    float* prevF  = (float*)alloc(ROWE * 4);
    char*  poolC  = (char*)alloc(4L * ROWE * 4); // 148.9 MB multi-purpose pool
    float* hpF    = (float*)alloc((long)M_ * 4 * 4 + 64);
    float* remF   = hpF + M_;
    float* nuF    = hpF + 2 * M_;
    float* uwF    = hpF + 3 * M_;
    int*   flags  = (int*)(hpF + 4 * M_);
    ushort_t* projH = (ushort_t*)alloc((long)H_ * H_ * 2);
    ushort_t* projL = (ushort_t*)alloc((long)H_ * H_ * 2);
    ushort_t* wqkvH = (ushort_t*)alloc((long)3 * H_ * H_ * 2);
    ushort_t* wqkvL = (ushort_t*)alloc((long)3 * H_ * H_ * 2);
    ushort_t* woH   = (ushort_t*)alloc((long)H_ * H_ * 2);
    ushort_t* woL   = (ushort_t*)alloc((long)H_ * H_ * 2);
    ushort_t* W1H   = (ushort_t*)alloc((long)FS_ * 3 * H_ * 2);
    ushort_t* W1L   = (ushort_t*)alloc((long)FS_ * 3 * H_ * 2);
    ushort_t* W2H   = (ushort_t*)alloc((long)H_ * 3 * FS_ * 2);
    ushort_t* W2L   = (ushort_t*)alloc((long)H_ * 3 * FS_ * 2);
    ushort_t* pooledH = (ushort_t*)alloc((long)B_ * H_ * 2);
    ushort_t* pooledL = (ushort_t*)alloc((long)B_ * H_ * 2);
    float* Ttab     = (float*)alloc((long)L_ * H_ * 4);
    float* Ptab     = (float*)alloc(6L * H_ * 4);

    // pool aliases (phases disjoint in time):
    ushort_t* xnH = (ushort_t*)poolC;
    ushort_t* xnL = xnH + ROWE;
    float* qkvF = (float*)(poolC + ROWE * 4);            // 3*ROWE floats
    ushort_t* ctxH = xnH;
    ushort_t* ctxL = xnL;
    ushort_t* xn2H = (ushort_t*)poolC;
    ushort_t* xn2L = xn2H + ROWE;
    ushort_t* y1H  = (ushort_t*)(poolC + ROWE * 4);
    ushort_t* y1L  = y1H + (long)MH_ * FS_;
    float* partF   = (float*)(poolC + ROWE * 4 + (long)MH_ * FS_ * 4);  // 2 x MH_*H_ f32
    ushort_t* xembH = (ushort_t*)poolC;
    ushort_t* xembL = xembH + ROWE;
    ushort_t* embH = (ushort_t*)poolC;
    ushort_t* embL = embH + (long)V_ * H_;

    dim3 blk(256);

    // --- init (ws re-poisoned every call) ---
    zero_f32<<<dim3((unsigned)((ROWE + 255) / 256)), blk, 0, stream>>>(prevF, ROWE);
    zero_f32<<<dim3((3 * M_ + 255) / 256), blk, 0, stream>>>(hpF, 3 * M_);
    zero_f32<<<dim3(1), blk, 0, stream>>>((float*)flags, 16);
    sig_prep<<<dim3(154), blk, 0, stream>>>(Ttab, Ptab);

    // --- weight prep: transpose + hi/lo split (q-scale 1/8 folded, bit-exact) ---
    wsplitT_kernel<<<dim3(1024), blk, 0, stream>>>(proj_w, projH, projL, H_, H_, 0, 1.f);
    wsplitT_kernel<<<dim3(1024), blk, 0, stream>>>(wq, wqkvH, wqkvL, H_, H_, 0, 0.125f);
    wsplitT_kernel<<<dim3(1024), blk, 0, stream>>>(wk, wqkvH, wqkvL, H_, H_, 512, 1.f);
    wsplitT_kernel<<<dim3(1024), blk, 0, stream>>>(wv, wqkvH, wqkvL, H_, H_, 1024, 1.f);
    wsplitT_kernel<<<dim3(1024), blk, 0, stream>>>(wo, woH, woL, H_, H_, 0, 1.f);
    convw_split_kernel<<<dim3(12288), blk, 0, stream>>>(c1_w, W1H, W1L, FS_, H_);
    convw_split_kernel<<<dim3(12288), blk, 0, stream>>>(c2_w, W2H, W2L, H_, FS_);

    // --- embedding + input projection ---
    embed_kernel<<<dim3(M_), blk, 0, stream>>>(story, query, emb, mask_p, xembH, xembL);
    gemm_s<64><<<dim3(H_ / 64, M_ / 128), blk, 0, stream>>>(
        xembH, xembL, H_, 0, projH, projL, H_, H_,
        nullptr, nullptr, 1.f, 0, 0, trunkF, nullptr, nullptr);

    // --- ACT loop: 6 steps with faithful any()-gate ---
    for (int t = 0; t < 6; t++) {
        gate_kernel<<<dim3(M_ / 256), blk, 0, stream>>>(hpF, nuF, flags + t);
        s_pr_kernel<<<dim3(M_ / 4), blk, 0, stream>>>(trunkF, Ttab, Ptab, p_w, p_b,
                                                      hpF, remF, nuF, uwF, flags + t, t);
        ln_kernel<<<dim3(M_ / 4), blk, 0, stream>>>(trunkF, ln1_g, ln1_b, xnH, xnL);
        gemm_s<128><<<dim3(1536 / 128, M_ / 128), blk, 0, stream>>>(
            xnH, xnL, H_, 0, wqkvH, wqkvL, 1536, H_,
            nullptr, nullptr, 1.f, 0, 0, qkvF, nullptr, nullptr);
        attn_kernel<<<dim3(B_ * NH_), blk, 0, stream>>>(qkvF, ctxH, ctxL);
        gemm_s<64><<<dim3(H_ / 64, M_ / 128), blk, 0, stream>>>(
            ctxH, ctxL, H_, 0, woH, woL, H_, H_,
            nullptr, trunkF, 1.f, 0, 0, trunkF, nullptr, nullptr);
        ln_kernel<<<dim3(M_ / 4), blk, 0, stream>>>(trunkF, ln2_g, ln2_b, xn2H, xn2L);
        for (int half = 0; half < 2; half++) {
            int ro = half * MH_;
            gemm_conv<0><<<dim3(32, 71), blk, 0, stream>>>(
                xn2H, xn2L, H_, ro, ro, W1H, W1L, FS_,
                c1_b, y1H, y1L, nullptr, 0, 512);
            gemm_conv<1><<<dim3(1136), blk, 0, stream>>>(
                y1H, y1L, FS_, 0, ro, W2H, W2L, H_,
                nullptr, nullptr, nullptr, partF, (long)MH_ * H_, 1024);
            conv2_reduce<<<dim3((unsigned)((long)MH_ * H_ / 4 / 256)), blk, 0, stream>>>(
                partF, (long)MH_ * H_, c2_b, trunkF, prevF, uwF, ro);
        }
    }

    // --- output head ---
    pooled_kernel<<<dim3(B_ * H_ / 256), blk, 0, stream>>>(prevF, pooledH, pooledL);
    esplit_kernel<<<dim3(64000), blk, 0, stream>>>(emb, embH, embL, (long)V_ * H_);
    gemm_s<64><<<dim3(V_ / 64, B_ / 128), blk, 0, stream>>>(
        pooledH, pooledL, H_, 0, embH, embL, V_, H_,
        out_b, nullptr, 1.f, 0, 0, outp, nullptr, nullptr);
    softmax_kernel<<<dim3(B_), blk, 0, stream>>>(outp, outp + (long)B_ * V_);
    tails_kernel<<<dim3((M_ + 255) / 256), blk, 0, stream>>>(remF, nuF, outp + 2L * B_ * V_);
}